// Round 5
// baseline (2585.745 us; speedup 1.0000x reference)
//
#include <hip/hip_runtime.h>
#include <cstddef>

#define BATCH 64
#define SEQL  197
#define EMB   768
#define NH    12
#define HDIM  64
#define NBLK  6
#define MLPD  3072
#define TOKS  12608   // BATCH*SEQL
#define PTOK  12544   // BATCH*196
#define ATT_SCALE 0.28867513459481287f  // 1/sqrt(H=12)
#define LOG2E 1.4426950408889634f

typedef short bf16x8 __attribute__((ext_vector_type(8)));
typedef float f32x4  __attribute__((ext_vector_type(4)));

__device__ inline float bf2f(unsigned short u) {
  union { unsigned int i; float f; } c; c.i = ((unsigned int)u) << 16; return c.f;
}
__device__ inline unsigned short f2bf(float f) {
  union { float f; unsigned int i; } c; c.f = f;
  unsigned int r = c.i + 0x7FFFu + ((c.i >> 16) & 1u);
  return (unsigned short)(r >> 16);
}

__device__ __forceinline__ void gload16(const unsigned short* g, void* l) {
  __builtin_amdgcn_global_load_lds(
      (const __attribute__((address_space(1))) unsigned int*)g,
      (__attribute__((address_space(3))) unsigned int*)l, 16, 0, 0);
}

// ---------------- patchify: images (B,3,224,224) -> patches (12544, 768) bf16 ----------------
__global__ __launch_bounds__(256) void patchify_kernel(const float* __restrict__ img,
                                                       unsigned short* __restrict__ out) {
  int i4 = blockIdx.x * 256 + threadIdx.x;    // < 12544*768/4
  int f4 = i4 % 192;
  int r  = i4 / 192;
  int b  = r / 196, t = r - b * 196;
  int f  = f4 * 4;
  int c  = f >> 8;
  int rem = f & 255;
  int iy = rem >> 4, ix = rem & 15;
  int py = t / 14, px = t - py * 14;
  const float* src = img + ((((size_t)b * 3 + c) * 224 + py * 16 + iy) * 224 + px * 16 + ix);
  float4 v = *(const float4*)src;
  ushort4 u;
  u.x = f2bf(v.x); u.y = f2bf(v.y); u.z = f2bf(v.z); u.w = f2bf(v.w);
  *(ushort4*)(out + (size_t)r * 768 + f) = u;
}

// ---------------- cls token + pos row 0 ----------------
__global__ __launch_bounds__(256) void clspos_kernel(const float* __restrict__ cls,
                                                     const float* __restrict__ pos,
                                                     float* __restrict__ X) {
  int idx = blockIdx.x * 256 + threadIdx.x;   // < 64*768
  int b = idx / 768, e = idx - b * 768;
  X[(size_t)b * SEQL * 768 + e] = cls[e] + pos[e];
}

// ---------------- weight transpose+convert: W (K,N) fp32 -> Wt (N,K) bf16 ----------------
__global__ __launch_bounds__(256) void wconv_kernel(const float* __restrict__ W,
                                                    unsigned short* __restrict__ Wt,
                                                    int K, int N) {
  __shared__ float t[32][33];
  int k0 = blockIdx.x * 32, n0 = blockIdx.y * 32;
  int kk = threadIdx.x >> 3, nn = (threadIdx.x & 7) * 4;
  float4 v = *(const float4*)&W[(size_t)(k0 + kk) * N + n0 + nn];
  t[nn + 0][kk] = v.x; t[nn + 1][kk] = v.y; t[nn + 2][kk] = v.z; t[nn + 3][kk] = v.w;
  __syncthreads();
  int nr = threadIdx.x >> 3, kc = (threadIdx.x & 7) * 4;
  ushort4 u;
  u.x = f2bf(t[nr][kc + 0]); u.y = f2bf(t[nr][kc + 1]);
  u.z = f2bf(t[nr][kc + 2]); u.w = f2bf(t[nr][kc + 3]);
  *(ushort4*)&Wt[(size_t)(n0 + nr) * K + k0 + kc] = u;
}

// ---------------- qkv weight transpose: W[m][h][d][e] fp32 -> Wt[(m*12+h)][e][d] bf16 ------
__global__ __launch_bounds__(256) void qwconv_kernel(const float* __restrict__ Wq,
                                                     const float* __restrict__ Wk,
                                                     const float* __restrict__ Wv,
                                                     unsigned short* __restrict__ Wt) {
  int mh = blockIdx.x;            // 0..35
  int m = mh / 12, h = mh - m * 12;
  const float* src = (m == 0 ? Wq : (m == 1 ? Wk : Wv)) + (size_t)h * 4096;
  unsigned short* dst = Wt + (size_t)mh * 4096;
  for (int idx = threadIdx.x; idx < 4096; idx += 256) {
    int d = idx >> 6, e = idx & 63;
    dst[e * 64 + d] = f2bf(src[idx]);
  }
}

// ---------------- 256x256 8-phase bf16 MFMA GEMM: C(M,N) = A(M,K) @ Bt(N,K)^T ----------
// 512 threads = 8 waves (2M x 4N); per-wave 128x64 out; BK=64, 4 phases/K-tile,
// dbuf LDS (128KB), counted vmcnt once per K-tile, chunk-XOR swizzle, setprio, XCD swizzle.
// MODE 0: X rows remapped b*197+1+t, C = acc + bias + pos[1+t]   (fp32 out)
// MODE 1: C = gelu(acc + bias)  -> bf16 out (mid, stride MLPD)
// MODE 2: C += acc + bias       -> fp32 residual (X, stride 768)
template<int MODE>
__global__ __launch_bounds__(512, 2) void gemm256(const unsigned short* __restrict__ A, int lda,
                                                  const unsigned short* __restrict__ Bt, int ldb,
                                                  void* __restrict__ Cv,
                                                  const float* __restrict__ bias,
                                                  const float* __restrict__ pos,
                                                  int M, int K, int GX) {
  __shared__ short As[2][16384];   // [buf][256 rows][64 k] bf16, chunk-swizzled (32KB each)
  __shared__ short Bs[2][16384];
  // bijective XCD swizzle (m204)
  const int nwg = gridDim.x;
  const int orig = blockIdx.x;
  const int qq = nwg >> 3, rr = nwg & 7, xcd = orig & 7, idx = orig >> 3;
  const int wg = (xcd < rr ? xcd * (qq + 1) : rr * (qq + 1) + (xcd - rr) * qq) + idx;
  const int m0 = (wg / GX) * 256;
  const int n0 = (wg % GX) * 256;

  const int tid  = threadIdx.x;
  const int wid  = tid >> 6, lane = tid & 63;
  const int wr   = wid >> 2, wc = wid & 3;     // 2M x 4N wave grid
  const int fr   = lane & 15;
  const int fq   = lane >> 4;
  const int frk  = fr & 7;
  const int srow = lane >> 3;                  // staging row-in-8 AND swizzle key
  const int schk = lane & 7;
  const int Mc   = M - 1;
  const int T    = K >> 6;

  f32x4 acc[8][4];
#pragma unroll
  for (int m = 0; m < 8; ++m)
#pragma unroll
    for (int n = 0; n < 4; ++n) acc[m][n] = (f32x4)0.f;

  auto STAGE_PART = [&](int bufi, int k0, int p) {
    int row = p * 64 + wid * 8 + srow;         // tile row 0..255
    int gra = m0 + row; if (gra > Mc) gra = Mc;
    gload16(A + (size_t)gra * lda + k0 + ((schk ^ srow) << 3),
            (char*)&As[bufi][0] + p * 8192 + wid * 1024);
    int grb = n0 + row;                        // N is a multiple of 256 for all callers
    gload16(Bt + (size_t)grb * ldb + k0 + ((schk ^ srow) << 3),
            (char*)&Bs[bufi][0] + p * 8192 + wid * 1024);
  };

  // prologue: stage tiles 0 and 1, wait only tile 0
#pragma unroll
  for (int p = 0; p < 4; ++p) STAGE_PART(0, 0, p);
#pragma unroll
  for (int p = 0; p < 4; ++p) STAGE_PART(1, 64, p);
  asm volatile("s_waitcnt vmcnt(8)" ::: "memory");
  __builtin_amdgcn_s_barrier();

  for (int t = 0; t < T; ++t) {
    const int b = t & 1;
    const short* Ab = &As[b][wr * 8192];       // this wave's A half (rows wr*128..)
    const short* Bb = &Bs[b][(wc >> 1) * 8192 + (wc & 1) * 4096];  // rows wc*64..
    const bool st = (t >= 1) && (t + 1 < T);
    const int nk = (t + 1) << 6;
#pragma unroll
    for (int p = 0; p < 4; ++p) {
      if (st) {
        if (p == 0) { STAGE_PART(b ^ 1, nk, 0); STAGE_PART(b ^ 1, nk, 1); }
        if (p == 1) { STAGE_PART(b ^ 1, nk, 2); STAGE_PART(b ^ 1, nk, 3); }
      }
      const int mg = p >> 1, ks = p & 1;
      const int slot = ((ks << 2) + fq) ^ frk;
      bf16x8 af[4], bfv[4];
#pragma unroll
      for (int mi = 0; mi < 4; ++mi)
        af[mi] = *(const bf16x8*)&Ab[((mg * 4 + mi) * 16 + fr) * 64 + slot * 8];
#pragma unroll
      for (int n = 0; n < 4; ++n)
        bfv[n] = *(const bf16x8*)&Bb[(n * 16 + fr) * 64 + slot * 8];
      __builtin_amdgcn_sched_barrier(0);
      __builtin_amdgcn_s_setprio(1);
#pragma unroll
      for (int mi = 0; mi < 4; ++mi)
#pragma unroll
        for (int n = 0; n < 4; ++n)
          acc[mg * 4 + mi][n] =
              __builtin_amdgcn_mfma_f32_16x16x32_bf16(af[mi], bfv[n], acc[mg * 4 + mi][n], 0, 0, 0);
      __builtin_amdgcn_s_setprio(0);
      __builtin_amdgcn_sched_barrier(0);
      if (p == 3) asm volatile("s_waitcnt vmcnt(0)" ::: "memory");
      __builtin_amdgcn_s_barrier();
    }
  }

  // epilogue: D row = fq*4 + j within 16x16 frag, col = fr  [m91-verified]
#pragma unroll
  for (int m = 0; m < 8; ++m) {
#pragma unroll
    for (int j = 0; j < 4; ++j) {
      int r = m0 + wr * 128 + m * 16 + (fq << 2) + j;
      if (r >= M) continue;
#pragma unroll
      for (int n = 0; n < 4; ++n) {
        int c = n0 + wc * 64 + n * 16 + fr;
        float v = acc[m][n][j] + bias[c];
        if (MODE == 0) {
          int bb = r / 196, tt = r - bb * 196;
          ((float*)Cv)[((size_t)bb * SEQL + 1 + tt) * 768 + c] = v + pos[(size_t)(1 + tt) * 768 + c];
        } else if (MODE == 1) {
          float g = 0.5f * v * (1.f + erff(v * 0.70710678118654752f));
          ((unsigned short*)Cv)[(size_t)r * MLPD + c] = f2bf(g);
        } else {
          ((float*)Cv)[(size_t)r * 768 + c] += v;
        }
      }
    }
  }
}

// ---------------- LayerNorm: one wave per token, fp32 in -> bf16 out ----------------
__global__ __launch_bounds__(256) void ln_kernel(const float* __restrict__ Xi,
                                                 unsigned short* __restrict__ Ho,
                                                 const float* __restrict__ g,
                                                 const float* __restrict__ bb) {
  int tok = blockIdx.x * 4 + (threadIdx.x >> 6);
  int lane = threadIdx.x & 63;
  const float* x = Xi + (size_t)tok * 768;
  float4 v0 = *(const float4*)(x + lane * 4);
  float4 v1 = *(const float4*)(x + 256 + lane * 4);
  float4 v2 = *(const float4*)(x + 512 + lane * 4);
  float s = v0.x + v0.y + v0.z + v0.w + v1.x + v1.y + v1.z + v1.w + v2.x + v2.y + v2.z + v2.w;
  float q = v0.x*v0.x + v0.y*v0.y + v0.z*v0.z + v0.w*v0.w
          + v1.x*v1.x + v1.y*v1.y + v1.z*v1.z + v1.w*v1.w
          + v2.x*v2.x + v2.y*v2.y + v2.z*v2.z + v2.w*v2.w;
#pragma unroll
  for (int o = 32; o > 0; o >>= 1) { s += __shfl_xor(s, o); q += __shfl_xor(q, o); }
  float mean = s * (1.f / 768.f);
  float var  = q * (1.f / 768.f) - mean * mean;
  float rs = rsqrtf(var + 1e-5f);
  unsigned short* outp = Ho + (size_t)tok * 768;
  float4 g0 = *(const float4*)(g + lane * 4);
  float4 g1 = *(const float4*)(g + 256 + lane * 4);
  float4 g2 = *(const float4*)(g + 512 + lane * 4);
  float4 b0 = *(const float4*)(bb + lane * 4);
  float4 b1 = *(const float4*)(bb + 256 + lane * 4);
  float4 b2 = *(const float4*)(bb + 512 + lane * 4);
  ushort4 s0, s1, s2;
  s0.x = f2bf((v0.x - mean) * rs * g0.x + b0.x); s0.y = f2bf((v0.y - mean) * rs * g0.y + b0.y);
  s0.z = f2bf((v0.z - mean) * rs * g0.z + b0.z); s0.w = f2bf((v0.w - mean) * rs * g0.w + b0.w);
  s1.x = f2bf((v1.x - mean) * rs * g1.x + b1.x); s1.y = f2bf((v1.y - mean) * rs * g1.y + b1.y);
  s1.z = f2bf((v1.z - mean) * rs * g1.z + b1.z); s1.w = f2bf((v1.w - mean) * rs * g1.w + b1.w);
  s2.x = f2bf((v2.x - mean) * rs * g2.x + b2.x); s2.y = f2bf((v2.y - mean) * rs * g2.y + b2.y);
  s2.z = f2bf((v2.z - mean) * rs * g2.z + b2.z); s2.w = f2bf((v2.w - mean) * rs * g2.w + b2.w);
  *(ushort4*)(outp + lane * 4) = s0;
  *(ushort4*)(outp + 256 + lane * 4) = s1;
  *(ushort4*)(outp + 512 + lane * 4) = s2;
}

// ---------------- MFMA QKV: WG = 64 tokens x head; wave = 16 tokens, q/k/v -----------
__global__ __launch_bounds__(256) void qkv_mfma(const unsigned short* __restrict__ Hb,
    const unsigned short* __restrict__ Wt,
    const float* __restrict__ bq, const float* __restrict__ bk, const float* __restrict__ bv,
    unsigned short* __restrict__ Qo, unsigned short* __restrict__ Ko,
    unsigned short* __restrict__ Vo) {
  const int h = blockIdx.y;
  const int tid = threadIdx.x, wv = tid >> 6, lane = tid & 63;
  const int fr = lane & 15, hi = lane >> 4;
  const int t0 = blockIdx.x * 64 + wv * 16;            // 197*64 = 12608 exact
  const unsigned short* arow = Hb + (size_t)(t0 + fr) * 768 + h * 64;
  bf16x8 a0 = *(const bf16x8*)(arow + hi * 8);
  bf16x8 a1 = *(const bf16x8*)(arow + 32 + hi * 8);
  f32x4 acc[3][4];
#pragma unroll
  for (int m = 0; m < 3; ++m)
#pragma unroll
    for (int n = 0; n < 4; ++n) acc[m][n] = (f32x4)0.f;
#pragma unroll
  for (int m = 0; m < 3; ++m) {
    const unsigned short* wb = Wt + (size_t)(m * 12 + h) * 4096;
#pragma unroll
    for (int n = 0; n < 4; ++n) {
      bf16x8 b0 = *(const bf16x8*)&wb[(n * 16 + fr) * 64 + hi * 8];
      bf16x8 b1 = *(const bf16x8*)&wb[(n * 16 + fr) * 64 + 32 + hi * 8];
      acc[m][n] = __builtin_amdgcn_mfma_f32_16x16x32_bf16(a0, b0, acc[m][n], 0, 0, 0);
      acc[m][n] = __builtin_amdgcn_mfma_f32_16x16x32_bf16(a1, b1, acc[m][n], 0, 0, 0);
    }
  }
#pragma unroll
  for (int m = 0; m < 3; ++m) {
    const float* bptr = (m == 0 ? bq : (m == 1 ? bk : bv)) + h * 64;
    unsigned short* optr = (m == 0 ? Qo : (m == 1 ? Ko : Vo));
    const float sc = (m == 0) ? ATT_SCALE : 1.f;
#pragma unroll
    for (int j = 0; j < 4; ++j) {
      int tk = t0 + hi * 4 + j;
      int b = tk / 197, s = tk - b * 197;
      size_t base_o = (((size_t)b * NH + h) * SEQL + s) * 64;
#pragma unroll
      for (int n = 0; n < 4; ++n)
        optr[base_o + n * 16 + fr] = f2bf((acc[m][n][j] + bptr[n * 16 + fr]) * sc);
    }
  }
}

// ---------------- MFMA attention: one WG (4 waves) per (b,h) ----------------
__global__ __launch_bounds__(256) void attn_kernel(const unsigned short* __restrict__ Q,
                                                   const unsigned short* __restrict__ Kg,
                                                   const unsigned short* __restrict__ Vg,
                                                   float* __restrict__ X) {
  __shared__ unsigned short Vt[64][232];      // V^T; cols 197..232 zero
  __shared__ unsigned short Pl[4][16][232];   // per-wave P; cols >=208 zero
  const int bh = blockIdx.x;
  const int b = bh / NH, h = bh - b * NH;
  const int tid = threadIdx.x, wv = tid >> 6, lane = tid & 63;
  const int fr = lane & 15, hi = lane >> 4;
  const unsigned short* Qp = Q  + (size_t)bh * SEQL * 64;
  const unsigned short* Kp = Kg + (size_t)bh * SEQL * 64;
  const unsigned short* Vp = Vg + (size_t)bh * SEQL * 64;

  for (int idx = tid; idx < SEQL * 16; idx += 256) {
    int s = idx >> 4, d4 = (idx & 15) * 4;
    ushort4 v = *(const ushort4*)&Vp[s * 64 + d4];
    Vt[d4 + 0][s] = v.x; Vt[d4 + 1][s] = v.y; Vt[d4 + 2][s] = v.z; Vt[d4 + 3][s] = v.w;
  }
  for (int idx = tid; idx < 64 * 35; idx += 256) {
    int d = idx / 35, c = 197 + idx % 35;
    Vt[d][c] = 0;
  }
  for (int idx = lane; idx < 16 * 24; idx += 64) {
    int r = idx / 24, c = 208 + idx % 24;
    Pl[wv][r][c] = 0;
  }
  __syncthreads();

  for (int qt = wv; qt < 13; qt += 4) {
    int qrow = qt * 16 + fr; if (qrow > 196) qrow = 196;
    bf16x8 qa0 = *(const bf16x8*)&Qp[qrow * 64 + hi * 8];
    bf16x8 qa1 = *(const bf16x8*)&Qp[qrow * 64 + 32 + hi * 8];
    f32x4 sc[13];
#pragma unroll
    for (int kt = 0; kt < 13; ++kt) {
      int krow = kt * 16 + fr; if (krow > 196) krow = 196;
      bf16x8 kb0 = *(const bf16x8*)&Kp[krow * 64 + hi * 8];
      bf16x8 kb1 = *(const bf16x8*)&Kp[krow * 64 + 32 + hi * 8];
      f32x4 a = (f32x4)0.f;
      a = __builtin_amdgcn_mfma_f32_16x16x32_bf16(qa0, kb0, a, 0, 0, 0);
      a = __builtin_amdgcn_mfma_f32_16x16x32_bf16(qa1, kb1, a, 0, 0, 0);
      sc[kt] = a;
    }
    float mx[4] = {-3e38f, -3e38f, -3e38f, -3e38f};
#pragma unroll
    for (int kt = 0; kt < 13; ++kt) {
      bool inval = (kt == 12) && (fr >= 5);
#pragma unroll
      for (int j = 0; j < 4; ++j) {
        float s = inval ? -3e38f : sc[kt][j];
        sc[kt][j] = s;
        mx[j] = fmaxf(mx[j], s);
      }
    }
#pragma unroll
    for (int o = 8; o > 0; o >>= 1)
#pragma unroll
      for (int j = 0; j < 4; ++j) mx[j] = fmaxf(mx[j], __shfl_xor(mx[j], o));
    float l[4] = {0.f, 0.f, 0.f, 0.f};
#pragma unroll
    for (int kt = 0; kt < 13; ++kt) {
#pragma unroll
      for (int j = 0; j < 4; ++j) {
        float p = exp2f((sc[kt][j] - mx[j]) * LOG2E);
        if ((kt == 12) && (fr >= 5)) p = 0.f;
        l[j] += p;
        Pl[wv][hi * 4 + j][kt * 16 + fr] = f2bf(p);
      }
    }
#pragma unroll
    for (int o = 8; o > 0; o >>= 1)
#pragma unroll
      for (int j = 0; j < 4; ++j) l[j] += __shfl_xor(l[j], o);
    f32x4 ov[4];
#pragma unroll
    for (int n = 0; n < 4; ++n) ov[n] = (f32x4)0.f;
#pragma unroll
    for (int kc = 0; kc < 7; ++kc) {
      bf16x8 pa = *(const bf16x8*)&Pl[wv][fr][kc * 32 + hi * 8];
#pragma unroll
      for (int n = 0; n < 4; ++n) {
        bf16x8 vb = *(const bf16x8*)&Vt[n * 16 + fr][kc * 32 + hi * 8];
        ov[n] = __builtin_amdgcn_mfma_f32_16x16x32_bf16(pa, vb, ov[n], 0, 0, 0);
      }
    }
#pragma unroll
    for (int j = 0; j < 4; ++j) {
      int r = qt * 16 + hi * 4 + j;
      if (r >= SEQL) continue;
      float inv = 1.f / l[j];
      float* xp = X + ((size_t)b * SEQL + r) * 768 + h * 64 + fr;
#pragma unroll
      for (int n = 0; n < 4; ++n) xp[n * 16] += ov[n][j] * inv;
    }
  }
}

// ---------------- head: cls @ Whead + bhead -> softmax ----------------
__global__ __launch_bounds__(64) void head_kernel(const float* __restrict__ X,
                                                  const float* __restrict__ Wh,
                                                  const float* __restrict__ bh,
                                                  float* __restrict__ out) {
  __shared__ float lg[10];
  int b = blockIdx.x, t = threadIdx.x;
  if (t < 10) {
    float acc = bh[t];
    const float* x = X + (size_t)b * SEQL * 768;
    for (int d = 0; d < 768; ++d) acc += x[d] * Wh[d * 10 + t];
    lg[t] = acc;
  }
  __syncthreads();
  if (t == 0) {
    float m = lg[0];
    for (int c = 1; c < 10; ++c) m = fmaxf(m, lg[c]);
    float ssum = 0.f;
    for (int c = 0; c < 10; ++c) ssum += expf(lg[c] - m);
    for (int c = 0; c < 10; ++c) out[b * 10 + c] = expf(lg[c] - m) / ssum;
  }
}

extern "C" void kernel_launch(void* const* d_in, const int* in_sizes, int n_in,
                              void* d_out, int out_size, void* d_ws, size_t ws_size,
                              hipStream_t stream) {
  const float* images = (const float*)d_in[0];
  const float* Wmap = (const float*)d_in[1];
  const float* bmap = (const float*)d_in[2];
  const float* cls  = (const float*)d_in[3];
  const float* pos  = (const float*)d_in[4];
  const float* ln1g = (const float*)d_in[5];
  const float* ln1b = (const float*)d_in[6];
  const float* Wq   = (const float*)d_in[7];
  const float* bq   = (const float*)d_in[8];
  const float* Wk   = (const float*)d_in[9];
  const float* bk   = (const float*)d_in[10];
  const float* Wv   = (const float*)d_in[11];
  const float* bv   = (const float*)d_in[12];
  const float* ln2g = (const float*)d_in[13];
  const float* ln2b = (const float*)d_in[14];
  const float* W1   = (const float*)d_in[15];
  const float* b1   = (const float*)d_in[16];
  const float* W2   = (const float*)d_in[17];
  const float* b2   = (const float*)d_in[18];
  const float* Wh   = (const float*)d_in[19];
  const float* bhd  = (const float*)d_in[20];
  float* out = (float*)d_out;

  const size_t ACT = (size_t)TOKS * 768;
  const size_t oX = 0;
  const size_t oHb = oX + ACT * 4;
  const size_t oR  = oHb + ACT * 2;
  const size_t oW1 = oR + 3 * ACT * 4;
  const size_t oW2 = oW1 + (size_t)768 * 3072 * 2;
  const size_t oWm = oW2 + (size_t)768 * 3072 * 2;
  const size_t oQW = oWm + (size_t)768 * 768 * 2;
  const size_t need = oQW + (size_t)36 * 4096 * 2;
  if (ws_size < need) return;

  char* ws = (char*)d_ws;
  float* X = (float*)(ws + oX);
  unsigned short* Hb = (unsigned short*)(ws + oHb);
  unsigned short* Qb = (unsigned short*)(ws + oR);
  unsigned short* Kb = Qb + ACT;
  unsigned short* Vb = Kb + ACT;
  unsigned short* mid = (unsigned short*)(ws + oR);
  unsigned short* patches = (unsigned short*)(ws + oR);
  unsigned short* W1t = (unsigned short*)(ws + oW1);
  unsigned short* W2t = (unsigned short*)(ws + oW2);
  unsigned short* Wmapt = (unsigned short*)(ws + oWm);
  unsigned short* QWt = (unsigned short*)(ws + oQW);

  wconv_kernel<<<dim3(24, 24), 256, 0, stream>>>(Wmap, Wmapt, 768, 768);
  patchify_kernel<<<9408, 256, 0, stream>>>(images, patches);
  clspos_kernel<<<192, 256, 0, stream>>>(cls, pos, X);
  // embed: M=12544 (49 blocks), N=768 (GX=3), K=768
  gemm256<0><<<147, 512, 0, stream>>>(patches, 768, Wmapt, 768, X, bmap, pos,
                                      PTOK, 768, 3);

  for (int i = 0; i < NBLK; ++i) {
    ln_kernel<<<3152, 256, 0, stream>>>(X, Hb, ln1g + i * 768, ln1b + i * 768);
    qwconv_kernel<<<36, 256, 0, stream>>>(Wq + (size_t)i * 49152, Wk + (size_t)i * 49152,
                                          Wv + (size_t)i * 49152, QWt);
    qkv_mfma<<<dim3(197, 12), 256, 0, stream>>>(Hb, QWt,
        bq + i * 768, bk + i * 768, bv + i * 768, Qb, Kb, Vb);
    attn_kernel<<<768, 256, 0, stream>>>(Qb, Kb, Vb, X);
    ln_kernel<<<3152, 256, 0, stream>>>(X, Hb, ln2g + i * 768, ln2b + i * 768);
    wconv_kernel<<<dim3(24, 96), 256, 0, stream>>>(W1 + (size_t)i * 2359296, W1t, 768, MLPD);
    wconv_kernel<<<dim3(96, 24), 256, 0, stream>>>(W2 + (size_t)i * 2359296, W2t, MLPD, 768);
    // MLP1: M=12608 (50 blocks, tail-guarded), N=3072 (GX=12), K=768
    gemm256<1><<<600, 512, 0, stream>>>(Hb, 768, W1t, 768, mid, b1 + i * MLPD,
                                        nullptr, TOKS, 768, 12);
    // MLP2: M=12608 (50 blocks), N=768 (GX=3), K=3072
    gemm256<2><<<150, 512, 0, stream>>>(mid, MLPD, W2t, MLPD, X, b2 + i * 768,
                                        nullptr, TOKS, 3072, 3);
  }
  head_kernel<<<64, 64, 0, stream>>>(X, Wh, bhd, out);
}

// Round 6
// 2320.823 us; speedup vs baseline: 1.1142x; 1.1142x over previous
//
#include <hip/hip_runtime.h>
#include <cstddef>

#define BATCH 64
#define SEQL  197
#define EMB   768
#define NH    12
#define HDIM  64
#define NBLK  6
#define MLPD  3072
#define TOKS  12608   // BATCH*SEQL
#define PTOK  12544   // BATCH*196
#define ATT_SCALE 0.28867513459481287f  // 1/sqrt(H=12)
#define LOG2E 1.4426950408889634f

typedef short bf16x8 __attribute__((ext_vector_type(8)));
typedef float f32x4  __attribute__((ext_vector_type(4)));

__device__ inline float bf2f(unsigned short u) {
  union { unsigned int i; float f; } c; c.i = ((unsigned int)u) << 16; return c.f;
}
__device__ inline unsigned short f2bf(float f) {
  union { float f; unsigned int i; } c; c.f = f;
  unsigned int r = c.i + 0x7FFFu + ((c.i >> 16) & 1u);
  return (unsigned short)(r >> 16);
}

__device__ __forceinline__ void gload16(const unsigned short* g, void* l) {
  __builtin_amdgcn_global_load_lds(
      (const __attribute__((address_space(1))) unsigned int*)g,
      (__attribute__((address_space(3))) unsigned int*)l, 16, 0, 0);
}

// ---------------- patchify: images (B,3,224,224) -> patches (12544, 768) bf16 ----------------
__global__ __launch_bounds__(256) void patchify_kernel(const float* __restrict__ img,
                                                       unsigned short* __restrict__ out) {
  int i4 = blockIdx.x * 256 + threadIdx.x;    // < 12544*768/4
  int f4 = i4 % 192;
  int r  = i4 / 192;
  int b  = r / 196, t = r - b * 196;
  int f  = f4 * 4;
  int c  = f >> 8;
  int rem = f & 255;
  int iy = rem >> 4, ix = rem & 15;
  int py = t / 14, px = t - py * 14;
  const float* src = img + ((((size_t)b * 3 + c) * 224 + py * 16 + iy) * 224 + px * 16 + ix);
  float4 v = *(const float4*)src;
  ushort4 u;
  u.x = f2bf(v.x); u.y = f2bf(v.y); u.z = f2bf(v.z); u.w = f2bf(v.w);
  *(ushort4*)(out + (size_t)r * 768 + f) = u;
}

// ---------------- cls token + pos row 0 ----------------
__global__ __launch_bounds__(256) void clspos_kernel(const float* __restrict__ cls,
                                                     const float* __restrict__ pos,
                                                     float* __restrict__ X) {
  int idx = blockIdx.x * 256 + threadIdx.x;   // < 64*768
  int b = idx / 768, e = idx - b * 768;
  X[(size_t)b * SEQL * 768 + e] = cls[e] + pos[e];
}

// ---------------- weight transpose+convert: W (K,N) fp32 -> Wt (N,K) bf16 ----------------
__global__ __launch_bounds__(256) void wconv_kernel(const float* __restrict__ W,
                                                    unsigned short* __restrict__ Wt,
                                                    int K, int N) {
  __shared__ float t[32][33];
  int k0 = blockIdx.x * 32, n0 = blockIdx.y * 32;
  int kk = threadIdx.x >> 3, nn = (threadIdx.x & 7) * 4;
  float4 v = *(const float4*)&W[(size_t)(k0 + kk) * N + n0 + nn];
  t[nn + 0][kk] = v.x; t[nn + 1][kk] = v.y; t[nn + 2][kk] = v.z; t[nn + 3][kk] = v.w;
  __syncthreads();
  int nr = threadIdx.x >> 3, kc = (threadIdx.x & 7) * 4;
  ushort4 u;
  u.x = f2bf(t[nr][kc + 0]); u.y = f2bf(t[nr][kc + 1]);
  u.z = f2bf(t[nr][kc + 2]); u.w = f2bf(t[nr][kc + 3]);
  *(ushort4*)&Wt[(size_t)(n0 + nr) * K + k0 + kc] = u;
}

// ---------------- qkv weight transpose: W[m][h][d][e] fp32 -> Wt[(m*12+h)][e][d] bf16 ------
__global__ __launch_bounds__(256) void qwconv_kernel(const float* __restrict__ Wq,
                                                     const float* __restrict__ Wk,
                                                     const float* __restrict__ Wv,
                                                     unsigned short* __restrict__ Wt) {
  int mh = blockIdx.x;            // 0..35
  int m = mh / 12, h = mh - m * 12;
  const float* src = (m == 0 ? Wq : (m == 1 ? Wk : Wv)) + (size_t)h * 4096;
  unsigned short* dst = Wt + (size_t)mh * 4096;
  for (int idx = threadIdx.x; idx < 4096; idx += 256) {
    int d = idx >> 6, e = idx & 63;
    dst[e * 64 + d] = f2bf(src[idx]);
  }
}

// ---------------- 128x128 bf16 MFMA GEMM (R3-verified single-buffer) ----------------
// MODE 0: X rows remapped b*197+1+t, C = acc + bias + pos[1+t]   (fp32 out)
// MODE 1: C = gelu(acc + bias)  -> bf16 out (mid, N=3072)
// MODE 2: C += acc + bias       -> fp32 residual (X, N=768)
template<int MODE>
__global__ __launch_bounds__(256) void gemm_mfma(const unsigned short* __restrict__ A, int lda,
                                                 const unsigned short* __restrict__ Bt, int ldb,
                                                 void* __restrict__ Cv,
                                                 const float* __restrict__ bias,
                                                 const float* __restrict__ pos,
                                                 int M, int N, int K) {
  __shared__ short As[8192];   // [128 rows][64 k] bf16, chunk-swizzled
  __shared__ short Bs[8192];
  const int tid  = threadIdx.x;
  const int wid  = tid >> 6, lane = tid & 63;
  const int wr   = wid >> 1, wc = wid & 1;
  const int fr   = lane & 15;
  const int fq   = lane >> 4;
  const int m0   = blockIdx.y * 128;
  const int n0   = blockIdx.x * 128;
  const int srow = lane >> 3;
  const int schk = lane & 7;
  const int Mc   = M - 1;

  f32x4 acc[4][4];
#pragma unroll
  for (int m = 0; m < 4; ++m)
#pragma unroll
    for (int n = 0; n < 4; ++n) acc[m][n] = (f32x4)0.f;

  for (int k0 = 0; k0 < K; k0 += 64) {
#pragma unroll
    for (int i = 0; i < 4; ++i) {
      int row = i * 32 + wid * 8 + srow;
      int gr = m0 + row; if (gr > Mc) gr = Mc;
      gload16(A + (size_t)gr * lda + k0 + ((schk ^ (row & 7)) << 3),
              (char*)As + i * 4096 + wid * 1024);
      gload16(Bt + (size_t)(n0 + row) * ldb + k0 + ((schk ^ (row & 7)) << 3),
              (char*)Bs + i * 4096 + wid * 1024);
    }
    __syncthreads();
#pragma unroll
    for (int ks = 0; ks < 2; ++ks) {
      bf16x8 af[4], bfr[4];
#pragma unroll
      for (int m = 0; m < 4; ++m) {
        int row = (wr << 6) + (m << 4) + fr;
        int ch = ((ks << 2) + fq) ^ (row & 7);
        af[m] = *(const bf16x8*)&As[(row << 6) + (ch << 3)];
      }
#pragma unroll
      for (int n = 0; n < 4; ++n) {
        int row = (wc << 6) + (n << 4) + fr;
        int ch = ((ks << 2) + fq) ^ (row & 7);
        bfr[n] = *(const bf16x8*)&Bs[(row << 6) + (ch << 3)];
      }
#pragma unroll
      for (int m = 0; m < 4; ++m)
#pragma unroll
        for (int n = 0; n < 4; ++n)
          acc[m][n] = __builtin_amdgcn_mfma_f32_16x16x32_bf16(af[m], bfr[n], acc[m][n], 0, 0, 0);
    }
    __syncthreads();
  }

#pragma unroll
  for (int m = 0; m < 4; ++m) {
#pragma unroll
    for (int j = 0; j < 4; ++j) {
      int r = m0 + (wr << 6) + (m << 4) + (fq << 2) + j;
      if (r >= M) continue;
#pragma unroll
      for (int n = 0; n < 4; ++n) {
        int c = n0 + (wc << 6) + (n << 4) + fr;
        float v = acc[m][n][j] + bias[c];
        if (MODE == 0) {
          int b = r / 196, t = r - b * 196;
          ((float*)Cv)[((size_t)b * SEQL + 1 + t) * 768 + c] = v + pos[(size_t)(1 + t) * 768 + c];
        } else if (MODE == 1) {
          float g = 0.5f * v * (1.f + erff(v * 0.70710678118654752f));
          ((unsigned short*)Cv)[(size_t)r * MLPD + c] = f2bf(g);
        } else {
          ((float*)Cv)[(size_t)r * 768 + c] += v;
        }
      }
    }
  }
}

// ---------------- 256x256 2-phase bf16 MFMA GEMM (MLP1) ----------------
// 512 threads = 8 waves (2M x 4N); per-wave 128x64 out; BK=64; dbuf 128KB;
// counted vmcnt(8) per K-tile (R4-verified schedule), chunk-XOR swizzle, XCD swizzle.
template<int MODE>
__global__ __launch_bounds__(512, 2) void gemm256(const unsigned short* __restrict__ A, int lda,
                                                  const unsigned short* __restrict__ Bt, int ldb,
                                                  void* __restrict__ Cv,
                                                  const float* __restrict__ bias,
                                                  int M, int K, int GX) {
  __shared__ short As[2][16384];   // [buf][256 rows][64 k] bf16, chunk-swizzled
  __shared__ short Bs[2][16384];
  // bijective XCD swizzle (m204)
  const int nwg = gridDim.x;
  const int orig = blockIdx.x;
  const int qq = nwg >> 3, rr = nwg & 7, xcd = orig & 7, bidx = orig >> 3;
  const int wg = (xcd < rr ? xcd * (qq + 1) : rr * (qq + 1) + (xcd - rr) * qq) + bidx;
  const int m0 = (wg / GX) * 256;
  const int n0 = (wg % GX) * 256;

  const int tid  = threadIdx.x;
  const int wid  = tid >> 6, lane = tid & 63;
  const int wr   = wid >> 2, wc = wid & 3;     // 2M x 4N wave grid
  const int fr   = lane & 15;
  const int fq   = lane >> 4;
  const int frk  = fr & 7;
  const int srow = lane >> 3;
  const int schk = lane & 7;
  const int Mc   = M - 1;
  const int T    = K >> 6;

  f32x4 acc[8][4];
#pragma unroll
  for (int m = 0; m < 8; ++m)
#pragma unroll
    for (int n = 0; n < 4; ++n) acc[m][n] = (f32x4)0.f;

  auto STAGE = [&](int bufi, int k0) {
#pragma unroll
    for (int p = 0; p < 4; ++p) {
      int row = p * 64 + wid * 8 + srow;       // tile row 0..255
      int gra = m0 + row; if (gra > Mc) gra = Mc;
      gload16(A + (size_t)gra * lda + k0 + ((schk ^ srow) << 3),
              (char*)&As[bufi][0] + p * 8192 + wid * 1024);
      int grb = n0 + row;                      // N multiple of 256 for all callers
      gload16(Bt + (size_t)grb * ldb + k0 + ((schk ^ srow) << 3),
              (char*)&Bs[bufi][0] + p * 8192 + wid * 1024);
    }
  };

  STAGE(0, 0);
  for (int t = 0; t < T; ++t) {
    const int b = t & 1;
    if (t + 1 < T) {
      STAGE(b ^ 1, (t + 1) << 6);
      asm volatile("s_waitcnt vmcnt(8)" ::: "memory");   // tile t ready; t+1 in flight
    } else {
      asm volatile("s_waitcnt vmcnt(0)" ::: "memory");
    }
    __builtin_amdgcn_s_barrier();
    const short* Ab = &As[b][wr * 8192];       // rows wr*128..wr*128+127
    const short* Bb = &Bs[b][wc * 4096];       // rows wc*64..wc*64+63
#pragma unroll
    for (int mg = 0; mg < 2; ++mg) {
#pragma unroll
      for (int ks = 0; ks < 2; ++ks) {
        const int slot = ((ks << 2) + fq) ^ frk;
        bf16x8 af[4], bfv[4];
#pragma unroll
        for (int mi = 0; mi < 4; ++mi)
          af[mi] = *(const bf16x8*)&Ab[((mg * 4 + mi) * 16 + fr) * 64 + slot * 8];
#pragma unroll
        for (int n = 0; n < 4; ++n)
          bfv[n] = *(const bf16x8*)&Bb[(n * 16 + fr) * 64 + slot * 8];
#pragma unroll
        for (int mi = 0; mi < 4; ++mi)
#pragma unroll
          for (int n = 0; n < 4; ++n)
            acc[mg * 4 + mi][n] =
                __builtin_amdgcn_mfma_f32_16x16x32_bf16(af[mi], bfv[n], acc[mg * 4 + mi][n], 0, 0, 0);
      }
    }
    __builtin_amdgcn_sched_barrier(0);
    __builtin_amdgcn_s_barrier();
  }

  // epilogue: D row = fq*4 + j within 16x16 frag, col = fr  [m91-verified]
#pragma unroll
  for (int m = 0; m < 8; ++m) {
#pragma unroll
    for (int j = 0; j < 4; ++j) {
      int r = m0 + wr * 128 + m * 16 + (fq << 2) + j;
      if (r >= M) continue;
#pragma unroll
      for (int n = 0; n < 4; ++n) {
        int c = n0 + wc * 64 + n * 16 + fr;
        float v = acc[m][n][j] + bias[c];
        if (MODE == 1) {
          float g = 0.5f * v * (1.f + erff(v * 0.70710678118654752f));
          ((unsigned short*)Cv)[(size_t)r * MLPD + c] = f2bf(g);
        } else {
          ((float*)Cv)[(size_t)r * 768 + c] += v;
        }
      }
    }
  }
}

// ---------------- LayerNorm: one wave per token, fp32 in -> bf16 out ----------------
__global__ __launch_bounds__(256) void ln_kernel(const float* __restrict__ Xi,
                                                 unsigned short* __restrict__ Ho,
                                                 const float* __restrict__ g,
                                                 const float* __restrict__ bb) {
  int tok = blockIdx.x * 4 + (threadIdx.x >> 6);
  int lane = threadIdx.x & 63;
  const float* x = Xi + (size_t)tok * 768;
  float4 v0 = *(const float4*)(x + lane * 4);
  float4 v1 = *(const float4*)(x + 256 + lane * 4);
  float4 v2 = *(const float4*)(x + 512 + lane * 4);
  float s = v0.x + v0.y + v0.z + v0.w + v1.x + v1.y + v1.z + v1.w + v2.x + v2.y + v2.z + v2.w;
  float q = v0.x*v0.x + v0.y*v0.y + v0.z*v0.z + v0.w*v0.w
          + v1.x*v1.x + v1.y*v1.y + v1.z*v1.z + v1.w*v1.w
          + v2.x*v2.x + v2.y*v2.y + v2.z*v2.z + v2.w*v2.w;
#pragma unroll
  for (int o = 32; o > 0; o >>= 1) { s += __shfl_xor(s, o); q += __shfl_xor(q, o); }
  float mean = s * (1.f / 768.f);
  float var  = q * (1.f / 768.f) - mean * mean;
  float rs = rsqrtf(var + 1e-5f);
  unsigned short* outp = Ho + (size_t)tok * 768;
  float4 g0 = *(const float4*)(g + lane * 4);
  float4 g1 = *(const float4*)(g + 256 + lane * 4);
  float4 g2 = *(const float4*)(g + 512 + lane * 4);
  float4 b0 = *(const float4*)(bb + lane * 4);
  float4 b1 = *(const float4*)(bb + 256 + lane * 4);
  float4 b2 = *(const float4*)(bb + 512 + lane * 4);
  ushort4 s0, s1, s2;
  s0.x = f2bf((v0.x - mean) * rs * g0.x + b0.x); s0.y = f2bf((v0.y - mean) * rs * g0.y + b0.y);
  s0.z = f2bf((v0.z - mean) * rs * g0.z + b0.z); s0.w = f2bf((v0.w - mean) * rs * g0.w + b0.w);
  s1.x = f2bf((v1.x - mean) * rs * g1.x + b1.x); s1.y = f2bf((v1.y - mean) * rs * g1.y + b1.y);
  s1.z = f2bf((v1.z - mean) * rs * g1.z + b1.z); s1.w = f2bf((v1.w - mean) * rs * g1.w + b1.w);
  s2.x = f2bf((v2.x - mean) * rs * g2.x + b2.x); s2.y = f2bf((v2.y - mean) * rs * g2.y + b2.y);
  s2.z = f2bf((v2.z - mean) * rs * g2.z + b2.z); s2.w = f2bf((v2.w - mean) * rs * g2.w + b2.w);
  *(ushort4*)(outp + lane * 4) = s0;
  *(ushort4*)(outp + 256 + lane * 4) = s1;
  *(ushort4*)(outp + 512 + lane * 4) = s2;
}

// ---------------- MFMA QKV: WG = 64 tokens x head; wave = 16 tokens, q/k/v -----------
__global__ __launch_bounds__(256) void qkv_mfma(const unsigned short* __restrict__ Hb,
    const unsigned short* __restrict__ Wt,
    const float* __restrict__ bq, const float* __restrict__ bk, const float* __restrict__ bv,
    unsigned short* __restrict__ Qo, unsigned short* __restrict__ Ko,
    unsigned short* __restrict__ Vo) {
  const int h = blockIdx.y;
  const int tid = threadIdx.x, wv = tid >> 6, lane = tid & 63;
  const int fr = lane & 15, hi = lane >> 4;
  const int t0 = blockIdx.x * 64 + wv * 16;            // 197*64 = 12608 exact
  const unsigned short* arow = Hb + (size_t)(t0 + fr) * 768 + h * 64;
  bf16x8 a0 = *(const bf16x8*)(arow + hi * 8);
  bf16x8 a1 = *(const bf16x8*)(arow + 32 + hi * 8);
  f32x4 acc[3][4];
#pragma unroll
  for (int m = 0; m < 3; ++m)
#pragma unroll
    for (int n = 0; n < 4; ++n) acc[m][n] = (f32x4)0.f;
#pragma unroll
  for (int m = 0; m < 3; ++m) {
    const unsigned short* wb = Wt + (size_t)(m * 12 + h) * 4096;
#pragma unroll
    for (int n = 0; n < 4; ++n) {
      bf16x8 b0 = *(const bf16x8*)&wb[(n * 16 + fr) * 64 + hi * 8];
      bf16x8 b1 = *(const bf16x8*)&wb[(n * 16 + fr) * 64 + 32 + hi * 8];
      acc[m][n] = __builtin_amdgcn_mfma_f32_16x16x32_bf16(a0, b0, acc[m][n], 0, 0, 0);
      acc[m][n] = __builtin_amdgcn_mfma_f32_16x16x32_bf16(a1, b1, acc[m][n], 0, 0, 0);
    }
  }
#pragma unroll
  for (int m = 0; m < 3; ++m) {
    const float* bptr = (m == 0 ? bq : (m == 1 ? bk : bv)) + h * 64;
    unsigned short* optr = (m == 0 ? Qo : (m == 1 ? Ko : Vo));
    const float sc = (m == 0) ? ATT_SCALE : 1.f;
#pragma unroll
    for (int j = 0; j < 4; ++j) {
      int tk = t0 + hi * 4 + j;
      int b = tk / 197, s = tk - b * 197;
      size_t base_o = (((size_t)b * NH + h) * SEQL + s) * 64;
#pragma unroll
      for (int n = 0; n < 4; ++n)
        optr[base_o + n * 16 + fr] = f2bf((acc[m][n][j] + bptr[n * 16 + fr]) * sc);
    }
  }
}

// ---------------- MFMA attention: one WG (4 waves) per (b,h) ----------------
__global__ __launch_bounds__(256) void attn_kernel(const unsigned short* __restrict__ Q,
                                                   const unsigned short* __restrict__ Kg,
                                                   const unsigned short* __restrict__ Vg,
                                                   float* __restrict__ X) {
  __shared__ unsigned short Vt[64][232];      // V^T; cols 197..232 zero
  __shared__ unsigned short Pl[4][16][232];   // per-wave P; cols >=208 zero
  const int bh = blockIdx.x;
  const int b = bh / NH, h = bh - b * NH;
  const int tid = threadIdx.x, wv = tid >> 6, lane = tid & 63;
  const int fr = lane & 15, hi = lane >> 4;
  const unsigned short* Qp = Q  + (size_t)bh * SEQL * 64;
  const unsigned short* Kp = Kg + (size_t)bh * SEQL * 64;
  const unsigned short* Vp = Vg + (size_t)bh * SEQL * 64;

  for (int idx = tid; idx < SEQL * 16; idx += 256) {
    int s = idx >> 4, d4 = (idx & 15) * 4;
    ushort4 v = *(const ushort4*)&Vp[s * 64 + d4];
    Vt[d4 + 0][s] = v.x; Vt[d4 + 1][s] = v.y; Vt[d4 + 2][s] = v.z; Vt[d4 + 3][s] = v.w;
  }
  for (int idx = tid; idx < 64 * 35; idx += 256) {
    int d = idx / 35, c = 197 + idx % 35;
    Vt[d][c] = 0;
  }
  for (int idx = lane; idx < 16 * 24; idx += 64) {
    int r = idx / 24, c = 208 + idx % 24;
    Pl[wv][r][c] = 0;
  }
  __syncthreads();

  for (int qt = wv; qt < 13; qt += 4) {
    int qrow = qt * 16 + fr; if (qrow > 196) qrow = 196;
    bf16x8 qa0 = *(const bf16x8*)&Qp[qrow * 64 + hi * 8];
    bf16x8 qa1 = *(const bf16x8*)&Qp[qrow * 64 + 32 + hi * 8];
    f32x4 sc[13];
#pragma unroll
    for (int kt = 0; kt < 13; ++kt) {
      int krow = kt * 16 + fr; if (krow > 196) krow = 196;
      bf16x8 kb0 = *(const bf16x8*)&Kp[krow * 64 + hi * 8];
      bf16x8 kb1 = *(const bf16x8*)&Kp[krow * 64 + 32 + hi * 8];
      f32x4 a = (f32x4)0.f;
      a = __builtin_amdgcn_mfma_f32_16x16x32_bf16(qa0, kb0, a, 0, 0, 0);
      a = __builtin_amdgcn_mfma_f32_16x16x32_bf16(qa1, kb1, a, 0, 0, 0);
      sc[kt] = a;
    }
    float mx[4] = {-3e38f, -3e38f, -3e38f, -3e38f};
#pragma unroll
    for (int kt = 0; kt < 13; ++kt) {
      bool inval = (kt == 12) && (fr >= 5);
#pragma unroll
      for (int j = 0; j < 4; ++j) {
        float s = inval ? -3e38f : sc[kt][j];
        sc[kt][j] = s;
        mx[j] = fmaxf(mx[j], s);
      }
    }
#pragma unroll
    for (int o = 8; o > 0; o >>= 1)
#pragma unroll
      for (int j = 0; j < 4; ++j) mx[j] = fmaxf(mx[j], __shfl_xor(mx[j], o));
    float l[4] = {0.f, 0.f, 0.f, 0.f};
#pragma unroll
    for (int kt = 0; kt < 13; ++kt) {
#pragma unroll
      for (int j = 0; j < 4; ++j) {
        float p = exp2f((sc[kt][j] - mx[j]) * LOG2E);
        if ((kt == 12) && (fr >= 5)) p = 0.f;
        l[j] += p;
        Pl[wv][hi * 4 + j][kt * 16 + fr] = f2bf(p);
      }
    }
#pragma unroll
    for (int o = 8; o > 0; o >>= 1)
#pragma unroll
      for (int j = 0; j < 4; ++j) l[j] += __shfl_xor(l[j], o);
    f32x4 ov[4];
#pragma unroll
    for (int n = 0; n < 4; ++n) ov[n] = (f32x4)0.f;
#pragma unroll
    for (int kc = 0; kc < 7; ++kc) {
      bf16x8 pa = *(const bf16x8*)&Pl[wv][fr][kc * 32 + hi * 8];
#pragma unroll
      for (int n = 0; n < 4; ++n) {
        bf16x8 vb = *(const bf16x8*)&Vt[n * 16 + fr][kc * 32 + hi * 8];
        ov[n] = __builtin_amdgcn_mfma_f32_16x16x32_bf16(pa, vb, ov[n], 0, 0, 0);
      }
    }
#pragma unroll
    for (int j = 0; j < 4; ++j) {
      int r = qt * 16 + hi * 4 + j;
      if (r >= SEQL) continue;
      float inv = 1.f / l[j];
      float* xp = X + ((size_t)b * SEQL + r) * 768 + h * 64 + fr;
#pragma unroll
      for (int n = 0; n < 4; ++n) xp[n * 16] += ov[n][j] * inv;
    }
  }
}

// ---------------- head: cls @ Whead + bhead -> softmax ----------------
__global__ __launch_bounds__(64) void head_kernel(const float* __restrict__ X,
                                                  const float* __restrict__ Wh,
                                                  const float* __restrict__ bh,
                                                  float* __restrict__ out) {
  __shared__ float lg[10];
  int b = blockIdx.x, t = threadIdx.x;
  if (t < 10) {
    float acc = bh[t];
    const float* x = X + (size_t)b * SEQL * 768;
    for (int d = 0; d < 768; ++d) acc += x[d] * Wh[d * 10 + t];
    lg[t] = acc;
  }
  __syncthreads();
  if (t == 0) {
    float m = lg[0];
    for (int c = 1; c < 10; ++c) m = fmaxf(m, lg[c]);
    float ssum = 0.f;
    for (int c = 0; c < 10; ++c) ssum += expf(lg[c] - m);
    for (int c = 0; c < 10; ++c) out[b * 10 + c] = expf(lg[c] - m) / ssum;
  }
}

extern "C" void kernel_launch(void* const* d_in, const int* in_sizes, int n_in,
                              void* d_out, int out_size, void* d_ws, size_t ws_size,
                              hipStream_t stream) {
  const float* images = (const float*)d_in[0];
  const float* Wmap = (const float*)d_in[1];
  const float* bmap = (const float*)d_in[2];
  const float* cls  = (const float*)d_in[3];
  const float* pos  = (const float*)d_in[4];
  const float* ln1g = (const float*)d_in[5];
  const float* ln1b = (const float*)d_in[6];
  const float* Wq   = (const float*)d_in[7];
  const float* bq   = (const float*)d_in[8];
  const float* Wk   = (const float*)d_in[9];
  const float* bk   = (const float*)d_in[10];
  const float* Wv   = (const float*)d_in[11];
  const float* bv   = (const float*)d_in[12];
  const float* ln2g = (const float*)d_in[13];
  const float* ln2b = (const float*)d_in[14];
  const float* W1   = (const float*)d_in[15];
  const float* b1   = (const float*)d_in[16];
  const float* W2   = (const float*)d_in[17];
  const float* b2   = (const float*)d_in[18];
  const float* Wh   = (const float*)d_in[19];
  const float* bhd  = (const float*)d_in[20];
  float* out = (float*)d_out;

  const size_t ACT = (size_t)TOKS * 768;
  const size_t oX = 0;
  const size_t oHb = oX + ACT * 4;
  const size_t oR  = oHb + ACT * 2;
  const size_t oW1 = oR + 3 * ACT * 4;
  const size_t oW2 = oW1 + (size_t)768 * 3072 * 2;
  const size_t oWm = oW2 + (size_t)768 * 3072 * 2;
  const size_t oQW = oWm + (size_t)768 * 768 * 2;
  const size_t need = oQW + (size_t)36 * 4096 * 2;
  if (ws_size < need) return;

  char* ws = (char*)d_ws;
  float* X = (float*)(ws + oX);
  unsigned short* Hb = (unsigned short*)(ws + oHb);
  unsigned short* Qb = (unsigned short*)(ws + oR);
  unsigned short* Kb = Qb + ACT;
  unsigned short* Vb = Kb + ACT;
  unsigned short* mid = (unsigned short*)(ws + oR);
  unsigned short* patches = (unsigned short*)(ws + oR);
  unsigned short* W1t = (unsigned short*)(ws + oW1);
  unsigned short* W2t = (unsigned short*)(ws + oW2);
  unsigned short* Wmapt = (unsigned short*)(ws + oWm);
  unsigned short* QWt = (unsigned short*)(ws + oQW);

  wconv_kernel<<<dim3(24, 24), 256, 0, stream>>>(Wmap, Wmapt, 768, 768);
  patchify_kernel<<<9408, 256, 0, stream>>>(images, patches);
  clspos_kernel<<<192, 256, 0, stream>>>(cls, pos, X);
  gemm_mfma<0><<<dim3(6, 98), 256, 0, stream>>>(patches, 768, Wmapt, 768, X, bmap, pos,
                                                PTOK, 768, 768);

  for (int i = 0; i < NBLK; ++i) {
    ln_kernel<<<3152, 256, 0, stream>>>(X, Hb, ln1g + i * 768, ln1b + i * 768);
    qwconv_kernel<<<36, 256, 0, stream>>>(Wq + (size_t)i * 49152, Wk + (size_t)i * 49152,
                                          Wv + (size_t)i * 49152, QWt);
    qkv_mfma<<<dim3(197, 12), 256, 0, stream>>>(Hb, QWt,
        bq + i * 768, bk + i * 768, bv + i * 768, Qb, Kb, Vb);
    attn_kernel<<<768, 256, 0, stream>>>(Qb, Kb, Vb, X);
    ln_kernel<<<3152, 256, 0, stream>>>(X, Hb, ln2g + i * 768, ln2b + i * 768);
    wconv_kernel<<<dim3(24, 96), 256, 0, stream>>>(W1 + (size_t)i * 2359296, W1t, 768, MLPD);
    wconv_kernel<<<dim3(96, 24), 256, 0, stream>>>(W2 + (size_t)i * 2359296, W2t, MLPD, 768);
    // MLP1: 256x256 tile, M=12608 (50), N=3072 (GX=12), K=768
    gemm256<1><<<600, 512, 0, stream>>>(Hb, 768, W1t, 768, mid, b1 + i * MLPD,
                                        TOKS, 768, 12);
    // MLP2: 128x128 tile (R3 config)
    gemm_mfma<2><<<dim3(6, 99), 256, 0, stream>>>(mid, MLPD, W2t, MLPD, X, b2 + i * 768,
                                                  nullptr, TOKS, 768, MLPD);
  }
  head_kernel<<<64, 64, 0, stream>>>(X, Wh, bhd, out);
}

// Round 7
// 1920.098 us; speedup vs baseline: 1.3467x; 1.2087x over previous
//
#include <hip/hip_runtime.h>
#include <cstddef>

#define BATCH 64
#define SEQL  197
#define EMB   768
#define NH    12
#define HDIM  64
#define NBLK  6
#define MLPD  3072
#define TOKS  12608   // BATCH*SEQL
#define PTOK  12544   // BATCH*196
#define ATT_SCALE 0.28867513459481287f  // 1/sqrt(H=12)
#define LOG2E 1.4426950408889634f

typedef short bf16x8 __attribute__((ext_vector_type(8)));
typedef float f32x4  __attribute__((ext_vector_type(4)));

__device__ inline float bf2f(unsigned short u) {
  union { unsigned int i; float f; } c; c.i = ((unsigned int)u) << 16; return c.f;
}
__device__ inline unsigned short f2bf(float f) {
  union { float f; unsigned int i; } c; c.f = f;
  unsigned int r = c.i + 0x7FFFu + ((c.i >> 16) & 1u);
  return (unsigned short)(r >> 16);
}

// gelu via A&S 7.1.26 erf (|err|<=1.5e-7): ~14 VALU ops vs ~25-30 for libm erff
__device__ __forceinline__ float gelu_f(float x) {
  float u = __builtin_fabsf(x) * 0.70710678118654752f;
  float t = __builtin_amdgcn_rcpf(__builtin_fmaf(0.3275911f, u, 1.0f));
  float p = __builtin_fmaf(1.061405429f, t, -1.453152027f);
  p = __builtin_fmaf(p, t, 1.421413741f);
  p = __builtin_fmaf(p, t, -0.284496736f);
  p = __builtin_fmaf(p, t, 0.254829592f);
  p = p * t;
  float e = __expf(-u * u);
  float er = __builtin_fmaf(-p, e, 1.0f);       // erf(|x|/sqrt2)
  er = __builtin_copysignf(er, x);
  return 0.5f * x * (1.0f + er);
}

__device__ __forceinline__ void gload16(const unsigned short* g, void* l) {
  __builtin_amdgcn_global_load_lds(
      (const __attribute__((address_space(1))) unsigned int*)g,
      (__attribute__((address_space(3))) unsigned int*)l, 16, 0, 0);
}

// ---------------- patchify: images (B,3,224,224) -> patches (12544, 768) bf16 ----------------
__global__ __launch_bounds__(256) void patchify_kernel(const float* __restrict__ img,
                                                       unsigned short* __restrict__ out) {
  int i4 = blockIdx.x * 256 + threadIdx.x;    // < 12544*768/4
  int f4 = i4 % 192;
  int r  = i4 / 192;
  int b  = r / 196, t = r - b * 196;
  int f  = f4 * 4;
  int c  = f >> 8;
  int rem = f & 255;
  int iy = rem >> 4, ix = rem & 15;
  int py = t / 14, px = t - py * 14;
  const float* src = img + ((((size_t)b * 3 + c) * 224 + py * 16 + iy) * 224 + px * 16 + ix);
  float4 v = *(const float4*)src;
  ushort4 u;
  u.x = f2bf(v.x); u.y = f2bf(v.y); u.z = f2bf(v.z); u.w = f2bf(v.w);
  *(ushort4*)(out + (size_t)r * 768 + f) = u;
}

// ---------------- cls token + pos row 0 ----------------
__global__ __launch_bounds__(256) void clspos_kernel(const float* __restrict__ cls,
                                                     const float* __restrict__ pos,
                                                     float* __restrict__ X) {
  int idx = blockIdx.x * 256 + threadIdx.x;   // < 64*768
  int b = idx / 768, e = idx - b * 768;
  X[(size_t)b * SEQL * 768 + e] = cls[e] + pos[e];
}

// ---------------- weight transpose+convert: W (K,N) fp32 -> Wt (N,K) bf16 ----------------
__global__ __launch_bounds__(256) void wconv_kernel(const float* __restrict__ W,
                                                    unsigned short* __restrict__ Wt,
                                                    int K, int N) {
  __shared__ float t[32][33];
  int k0 = blockIdx.x * 32, n0 = blockIdx.y * 32;
  int kk = threadIdx.x >> 3, nn = (threadIdx.x & 7) * 4;
  float4 v = *(const float4*)&W[(size_t)(k0 + kk) * N + n0 + nn];
  t[nn + 0][kk] = v.x; t[nn + 1][kk] = v.y; t[nn + 2][kk] = v.z; t[nn + 3][kk] = v.w;
  __syncthreads();
  int nr = threadIdx.x >> 3, kc = (threadIdx.x & 7) * 4;
  ushort4 u;
  u.x = f2bf(t[nr][kc + 0]); u.y = f2bf(t[nr][kc + 1]);
  u.z = f2bf(t[nr][kc + 2]); u.w = f2bf(t[nr][kc + 3]);
  *(ushort4*)&Wt[(size_t)(n0 + nr) * K + k0 + kc] = u;
}

// ---------------- qkv weight transpose: W[m][h][d][e] fp32 -> Wt[(m*12+h)][e][d] bf16 ------
__global__ __launch_bounds__(256) void qwconv_kernel(const float* __restrict__ Wq,
                                                     const float* __restrict__ Wk,
                                                     const float* __restrict__ Wv,
                                                     unsigned short* __restrict__ Wt) {
  int mh = blockIdx.x;            // 0..35
  int m = mh / 12, h = mh - m * 12;
  const float* src = (m == 0 ? Wq : (m == 1 ? Wk : Wv)) + (size_t)h * 4096;
  unsigned short* dst = Wt + (size_t)mh * 4096;
  for (int idx = threadIdx.x; idx < 4096; idx += 256) {
    int d = idx >> 6, e = idx & 63;
    dst[e * 64 + d] = f2bf(src[idx]);
  }
}

// ---------------- 128x128 bf16 MFMA GEMM (R3-verified single-buffer) ----------------
// MODE 0: X rows remapped b*197+1+t, C = acc + bias + pos[1+t]   (fp32 out)
// MODE 1: C = gelu(acc + bias)  -> bf16 out (mid, N=3072)
// MODE 2: C += acc + bias       -> fp32 residual (X, N=768)
template<int MODE>
__global__ __launch_bounds__(256) void gemm_mfma(const unsigned short* __restrict__ A, int lda,
                                                 const unsigned short* __restrict__ Bt, int ldb,
                                                 void* __restrict__ Cv,
                                                 const float* __restrict__ bias,
                                                 const float* __restrict__ pos,
                                                 int M, int N, int K) {
  __shared__ short As[8192];   // [128 rows][64 k] bf16, chunk-swizzled
  __shared__ short Bs[8192];
  const int tid  = threadIdx.x;
  const int wid  = tid >> 6, lane = tid & 63;
  const int wr   = wid >> 1, wc = wid & 1;
  const int fr   = lane & 15;
  const int fq   = lane >> 4;
  const int m0   = blockIdx.y * 128;
  const int n0   = blockIdx.x * 128;
  const int srow = lane >> 3;
  const int schk = lane & 7;
  const int Mc   = M - 1;

  f32x4 acc[4][4];
#pragma unroll
  for (int m = 0; m < 4; ++m)
#pragma unroll
    for (int n = 0; n < 4; ++n) acc[m][n] = (f32x4)0.f;

  for (int k0 = 0; k0 < K; k0 += 64) {
#pragma unroll
    for (int i = 0; i < 4; ++i) {
      int row = i * 32 + wid * 8 + srow;
      int gr = m0 + row; if (gr > Mc) gr = Mc;
      gload16(A + (size_t)gr * lda + k0 + ((schk ^ (row & 7)) << 3),
              (char*)As + i * 4096 + wid * 1024);
      gload16(Bt + (size_t)(n0 + row) * ldb + k0 + ((schk ^ (row & 7)) << 3),
              (char*)Bs + i * 4096 + wid * 1024);
    }
    __syncthreads();
#pragma unroll
    for (int ks = 0; ks < 2; ++ks) {
      bf16x8 af[4], bfr[4];
#pragma unroll
      for (int m = 0; m < 4; ++m) {
        int row = (wr << 6) + (m << 4) + fr;
        int ch = ((ks << 2) + fq) ^ (row & 7);
        af[m] = *(const bf16x8*)&As[(row << 6) + (ch << 3)];
      }
#pragma unroll
      for (int n = 0; n < 4; ++n) {
        int row = (wc << 6) + (n << 4) + fr;
        int ch = ((ks << 2) + fq) ^ (row & 7);
        bfr[n] = *(const bf16x8*)&Bs[(row << 6) + (ch << 3)];
      }
#pragma unroll
      for (int m = 0; m < 4; ++m)
#pragma unroll
        for (int n = 0; n < 4; ++n)
          acc[m][n] = __builtin_amdgcn_mfma_f32_16x16x32_bf16(af[m], bfr[n], acc[m][n], 0, 0, 0);
    }
    __syncthreads();
  }

#pragma unroll
  for (int m = 0; m < 4; ++m) {
#pragma unroll
    for (int j = 0; j < 4; ++j) {
      int r = m0 + (wr << 6) + (m << 4) + (fq << 2) + j;
      if (r >= M) continue;
#pragma unroll
      for (int n = 0; n < 4; ++n) {
        int c = n0 + (wc << 6) + (n << 4) + fr;
        float v = acc[m][n][j] + bias[c];
        if (MODE == 0) {
          int b = r / 196, t = r - b * 196;
          ((float*)Cv)[((size_t)b * SEQL + 1 + t) * 768 + c] = v + pos[(size_t)(1 + t) * 768 + c];
        } else if (MODE == 1) {
          ((unsigned short*)Cv)[(size_t)r * MLPD + c] = f2bf(gelu_f(v));
        } else {
          ((float*)Cv)[(size_t)r * 768 + c] += v;
        }
      }
    }
  }
}

// ---------------- LayerNorm: one wave per token, fp32 in -> bf16 out ----------------
__global__ __launch_bounds__(256) void ln_kernel(const float* __restrict__ Xi,
                                                 unsigned short* __restrict__ Ho,
                                                 const float* __restrict__ g,
                                                 const float* __restrict__ bb) {
  int tok = blockIdx.x * 4 + (threadIdx.x >> 6);
  int lane = threadIdx.x & 63;
  const float* x = Xi + (size_t)tok * 768;
  float4 v0 = *(const float4*)(x + lane * 4);
  float4 v1 = *(const float4*)(x + 256 + lane * 4);
  float4 v2 = *(const float4*)(x + 512 + lane * 4);
  float s = v0.x + v0.y + v0.z + v0.w + v1.x + v1.y + v1.z + v1.w + v2.x + v2.y + v2.z + v2.w;
  float q = v0.x*v0.x + v0.y*v0.y + v0.z*v0.z + v0.w*v0.w
          + v1.x*v1.x + v1.y*v1.y + v1.z*v1.z + v1.w*v1.w
          + v2.x*v2.x + v2.y*v2.y + v2.z*v2.z + v2.w*v2.w;
#pragma unroll
  for (int o = 32; o > 0; o >>= 1) { s += __shfl_xor(s, o); q += __shfl_xor(q, o); }
  float mean = s * (1.f / 768.f);
  float var  = q * (1.f / 768.f) - mean * mean;
  float rs = rsqrtf(var + 1e-5f);
  unsigned short* outp = Ho + (size_t)tok * 768;
  float4 g0 = *(const float4*)(g + lane * 4);
  float4 g1 = *(const float4*)(g + 256 + lane * 4);
  float4 g2 = *(const float4*)(g + 512 + lane * 4);
  float4 b0 = *(const float4*)(bb + lane * 4);
  float4 b1 = *(const float4*)(bb + 256 + lane * 4);
  float4 b2 = *(const float4*)(bb + 512 + lane * 4);
  ushort4 s0, s1, s2;
  s0.x = f2bf((v0.x - mean) * rs * g0.x + b0.x); s0.y = f2bf((v0.y - mean) * rs * g0.y + b0.y);
  s0.z = f2bf((v0.z - mean) * rs * g0.z + b0.z); s0.w = f2bf((v0.w - mean) * rs * g0.w + b0.w);
  s1.x = f2bf((v1.x - mean) * rs * g1.x + b1.x); s1.y = f2bf((v1.y - mean) * rs * g1.y + b1.y);
  s1.z = f2bf((v1.z - mean) * rs * g1.z + b1.z); s1.w = f2bf((v1.w - mean) * rs * g1.w + b1.w);
  s2.x = f2bf((v2.x - mean) * rs * g2.x + b2.x); s2.y = f2bf((v2.y - mean) * rs * g2.y + b2.y);
  s2.z = f2bf((v2.z - mean) * rs * g2.z + b2.z); s2.w = f2bf((v2.w - mean) * rs * g2.w + b2.w);
  *(ushort4*)(outp + lane * 4) = s0;
  *(ushort4*)(outp + 256 + lane * 4) = s1;
  *(ushort4*)(outp + 512 + lane * 4) = s2;
}

// ---------------- MFMA QKV: WG = 64 tokens x head; wave = 16 tokens, q/k/v -----------
__global__ __launch_bounds__(256) void qkv_mfma(const unsigned short* __restrict__ Hb,
    const unsigned short* __restrict__ Wt,
    const float* __restrict__ bq, const float* __restrict__ bk, const float* __restrict__ bv,
    unsigned short* __restrict__ Qo, unsigned short* __restrict__ Ko,
    unsigned short* __restrict__ Vo) {
  const int h = blockIdx.y;
  const int tid = threadIdx.x, wv = tid >> 6, lane = tid & 63;
  const int fr = lane & 15, hi = lane >> 4;
  const int t0 = blockIdx.x * 64 + wv * 16;            // 197*64 = 12608 exact
  const unsigned short* arow = Hb + (size_t)(t0 + fr) * 768 + h * 64;
  bf16x8 a0 = *(const bf16x8*)(arow + hi * 8);
  bf16x8 a1 = *(const bf16x8*)(arow + 32 + hi * 8);
  f32x4 acc[3][4];
#pragma unroll
  for (int m = 0; m < 3; ++m)
#pragma unroll
    for (int n = 0; n < 4; ++n) acc[m][n] = (f32x4)0.f;
#pragma unroll
  for (int m = 0; m < 3; ++m) {
    const unsigned short* wb = Wt + (size_t)(m * 12 + h) * 4096;
#pragma unroll
    for (int n = 0; n < 4; ++n) {
      bf16x8 b0 = *(const bf16x8*)&wb[(n * 16 + fr) * 64 + hi * 8];
      bf16x8 b1 = *(const bf16x8*)&wb[(n * 16 + fr) * 64 + 32 + hi * 8];
      acc[m][n] = __builtin_amdgcn_mfma_f32_16x16x32_bf16(a0, b0, acc[m][n], 0, 0, 0);
      acc[m][n] = __builtin_amdgcn_mfma_f32_16x16x32_bf16(a1, b1, acc[m][n], 0, 0, 0);
    }
  }
#pragma unroll
  for (int m = 0; m < 3; ++m) {
    const float* bptr = (m == 0 ? bq : (m == 1 ? bk : bv)) + h * 64;
    unsigned short* optr = (m == 0 ? Qo : (m == 1 ? Ko : Vo));
    const float sc = (m == 0) ? ATT_SCALE : 1.f;
#pragma unroll
    for (int j = 0; j < 4; ++j) {
      int tk = t0 + hi * 4 + j;
      int b = tk / 197, s = tk - b * 197;
      size_t base_o = (((size_t)b * NH + h) * SEQL + s) * 64;
#pragma unroll
      for (int n = 0; n < 4; ++n)
        optr[base_o + n * 16 + fr] = f2bf((acc[m][n][j] + bptr[n * 16 + fr]) * sc);
    }
  }
}

// ---------------- MFMA attention: one WG (4 waves) per (b,h) ----------------
__global__ __launch_bounds__(256) void attn_kernel(const unsigned short* __restrict__ Q,
                                                   const unsigned short* __restrict__ Kg,
                                                   const unsigned short* __restrict__ Vg,
                                                   float* __restrict__ X) {
  __shared__ unsigned short Vt[64][232];      // V^T; cols 197..232 zero
  __shared__ unsigned short Pl[4][16][232];   // per-wave P; cols >=208 zero
  const int bh = blockIdx.x;
  const int b = bh / NH, h = bh - b * NH;
  const int tid = threadIdx.x, wv = tid >> 6, lane = tid & 63;
  const int fr = lane & 15, hi = lane >> 4;
  const unsigned short* Qp = Q  + (size_t)bh * SEQL * 64;
  const unsigned short* Kp = Kg + (size_t)bh * SEQL * 64;
  const unsigned short* Vp = Vg + (size_t)bh * SEQL * 64;

  for (int idx = tid; idx < SEQL * 16; idx += 256) {
    int s = idx >> 4, d4 = (idx & 15) * 4;
    ushort4 v = *(const ushort4*)&Vp[s * 64 + d4];
    Vt[d4 + 0][s] = v.x; Vt[d4 + 1][s] = v.y; Vt[d4 + 2][s] = v.z; Vt[d4 + 3][s] = v.w;
  }
  for (int idx = tid; idx < 64 * 35; idx += 256) {
    int d = idx / 35, c = 197 + idx % 35;
    Vt[d][c] = 0;
  }
  for (int idx = lane; idx < 16 * 24; idx += 64) {
    int r = idx / 24, c = 208 + idx % 24;
    Pl[wv][r][c] = 0;
  }
  __syncthreads();

  for (int qt = wv; qt < 13; qt += 4) {
    int qrow = qt * 16 + fr; if (qrow > 196) qrow = 196;
    bf16x8 qa0 = *(const bf16x8*)&Qp[qrow * 64 + hi * 8];
    bf16x8 qa1 = *(const bf16x8*)&Qp[qrow * 64 + 32 + hi * 8];
    f32x4 sc[13];
#pragma unroll
    for (int kt = 0; kt < 13; ++kt) {
      int krow = kt * 16 + fr; if (krow > 196) krow = 196;
      bf16x8 kb0 = *(const bf16x8*)&Kp[krow * 64 + hi * 8];
      bf16x8 kb1 = *(const bf16x8*)&Kp[krow * 64 + 32 + hi * 8];
      f32x4 a = (f32x4)0.f;
      a = __builtin_amdgcn_mfma_f32_16x16x32_bf16(qa0, kb0, a, 0, 0, 0);
      a = __builtin_amdgcn_mfma_f32_16x16x32_bf16(qa1, kb1, a, 0, 0, 0);
      sc[kt] = a;
    }
    float mx[4] = {-3e38f, -3e38f, -3e38f, -3e38f};
#pragma unroll
    for (int kt = 0; kt < 13; ++kt) {
      bool inval = (kt == 12) && (fr >= 5);
#pragma unroll
      for (int j = 0; j < 4; ++j) {
        float s = inval ? -3e38f : sc[kt][j];
        sc[kt][j] = s;
        mx[j] = fmaxf(mx[j], s);
      }
    }
#pragma unroll
    for (int o = 8; o > 0; o >>= 1)
#pragma unroll
      for (int j = 0; j < 4; ++j) mx[j] = fmaxf(mx[j], __shfl_xor(mx[j], o));
    float l[4] = {0.f, 0.f, 0.f, 0.f};
#pragma unroll
    for (int kt = 0; kt < 13; ++kt) {
#pragma unroll
      for (int j = 0; j < 4; ++j) {
        float p = exp2f((sc[kt][j] - mx[j]) * LOG2E);
        if ((kt == 12) && (fr >= 5)) p = 0.f;
        l[j] += p;
        Pl[wv][hi * 4 + j][kt * 16 + fr] = f2bf(p);
      }
    }
#pragma unroll
    for (int o = 8; o > 0; o >>= 1)
#pragma unroll
      for (int j = 0; j < 4; ++j) l[j] += __shfl_xor(l[j], o);
    f32x4 ov[4];
#pragma unroll
    for (int n = 0; n < 4; ++n) ov[n] = (f32x4)0.f;
#pragma unroll
    for (int kc = 0; kc < 7; ++kc) {
      bf16x8 pa = *(const bf16x8*)&Pl[wv][fr][kc * 32 + hi * 8];
#pragma unroll
      for (int n = 0; n < 4; ++n) {
        bf16x8 vb = *(const bf16x8*)&Vt[n * 16 + fr][kc * 32 + hi * 8];
        ov[n] = __builtin_amdgcn_mfma_f32_16x16x32_bf16(pa, vb, ov[n], 0, 0, 0);
      }
    }
#pragma unroll
    for (int j = 0; j < 4; ++j) {
      int r = qt * 16 + hi * 4 + j;
      if (r >= SEQL) continue;
      float inv = 1.f / l[j];
      float* xp = X + ((size_t)b * SEQL + r) * 768 + h * 64 + fr;
#pragma unroll
      for (int n = 0; n < 4; ++n) xp[n * 16] += ov[n][j] * inv;
    }
  }
}

// ---------------- head: cls @ Whead + bhead -> softmax ----------------
__global__ __launch_bounds__(64) void head_kernel(const float* __restrict__ X,
                                                  const float* __restrict__ Wh,
                                                  const float* __restrict__ bh,
                                                  float* __restrict__ out) {
  __shared__ float lg[10];
  int b = blockIdx.x, t = threadIdx.x;
  if (t < 10) {
    float acc = bh[t];
    const float* x = X + (size_t)b * SEQL * 768;
    for (int d = 0; d < 768; ++d) acc += x[d] * Wh[d * 10 + t];
    lg[t] = acc;
  }
  __syncthreads();
  if (t == 0) {
    float m = lg[0];
    for (int c = 1; c < 10; ++c) m = fmaxf(m, lg[c]);
    float ssum = 0.f;
    for (int c = 0; c < 10; ++c) ssum += expf(lg[c] - m);
    for (int c = 0; c < 10; ++c) out[b * 10 + c] = expf(lg[c] - m) / ssum;
  }
}

extern "C" void kernel_launch(void* const* d_in, const int* in_sizes, int n_in,
                              void* d_out, int out_size, void* d_ws, size_t ws_size,
                              hipStream_t stream) {
  const float* images = (const float*)d_in[0];
  const float* Wmap = (const float*)d_in[1];
  const float* bmap = (const float*)d_in[2];
  const float* cls  = (const float*)d_in[3];
  const float* pos  = (const float*)d_in[4];
  const float* ln1g = (const float*)d_in[5];
  const float* ln1b = (const float*)d_in[6];
  const float* Wq   = (const float*)d_in[7];
  const float* bq   = (const float*)d_in[8];
  const float* Wk   = (const float*)d_in[9];
  const float* bk   = (const float*)d_in[10];
  const float* Wv   = (const float*)d_in[11];
  const float* bv   = (const float*)d_in[12];
  const float* ln2g = (const float*)d_in[13];
  const float* ln2b = (const float*)d_in[14];
  const float* W1   = (const float*)d_in[15];
  const float* b1   = (const float*)d_in[16];
  const float* W2   = (const float*)d_in[17];
  const float* b2   = (const float*)d_in[18];
  const float* Wh   = (const float*)d_in[19];
  const float* bhd  = (const float*)d_in[20];
  float* out = (float*)d_out;

  const size_t ACT = (size_t)TOKS * 768;
  const size_t oX = 0;
  const size_t oHb = oX + ACT * 4;
  const size_t oR  = oHb + ACT * 2;
  const size_t oW1 = oR + 3 * ACT * 4;
  const size_t oW2 = oW1 + (size_t)768 * 3072 * 2;
  const size_t oWm = oW2 + (size_t)768 * 3072 * 2;
  const size_t oQW = oWm + (size_t)768 * 768 * 2;
  const size_t need = oQW + (size_t)36 * 4096 * 2;
  if (ws_size < need) return;

  char* ws = (char*)d_ws;
  float* X = (float*)(ws + oX);
  unsigned short* Hb = (unsigned short*)(ws + oHb);
  unsigned short* Qb = (unsigned short*)(ws + oR);
  unsigned short* Kb = Qb + ACT;
  unsigned short* Vb = Kb + ACT;
  unsigned short* mid = (unsigned short*)(ws + oR);
  unsigned short* patches = (unsigned short*)(ws + oR);
  unsigned short* W1t = (unsigned short*)(ws + oW1);
  unsigned short* W2t = (unsigned short*)(ws + oW2);
  unsigned short* Wmapt = (unsigned short*)(ws + oWm);
  unsigned short* QWt = (unsigned short*)(ws + oQW);

  wconv_kernel<<<dim3(24, 24), 256, 0, stream>>>(Wmap, Wmapt, 768, 768);
  patchify_kernel<<<9408, 256, 0, stream>>>(images, patches);
  clspos_kernel<<<192, 256, 0, stream>>>(cls, pos, X);
  gemm_mfma<0><<<dim3(6, 98), 256, 0, stream>>>(patches, 768, Wmapt, 768, X, bmap, pos,
                                                PTOK, 768, 768);

  for (int i = 0; i < NBLK; ++i) {
    ln_kernel<<<3152, 256, 0, stream>>>(X, Hb, ln1g + i * 768, ln1b + i * 768);
    qwconv_kernel<<<36, 256, 0, stream>>>(Wq + (size_t)i * 49152, Wk + (size_t)i * 49152,
                                          Wv + (size_t)i * 49152, QWt);
    qkv_mfma<<<dim3(197, 12), 256, 0, stream>>>(Hb, QWt,
        bq + i * 768, bk + i * 768, bv + i * 768, Qb, Kb, Vb);
    attn_kernel<<<768, 256, 0, stream>>>(Qb, Kb, Vb, X);
    ln_kernel<<<3152, 256, 0, stream>>>(X, Hb, ln2g + i * 768, ln2b + i * 768);
    wconv_kernel<<<dim3(24, 96), 256, 0, stream>>>(W1 + (size_t)i * 2359296, W1t, 768, MLPD);
    wconv_kernel<<<dim3(96, 24), 256, 0, stream>>>(W2 + (size_t)i * 2359296, W2t, MLPD, 768);
    // MLP1: 128x128 tile (R3-exact config) + cheap gelu epilogue
    gemm_mfma<1><<<dim3(24, 99), 256, 0, stream>>>(Hb, 768, W1t, 768, mid, b1 + i * MLPD,
                                                   nullptr, TOKS, MLPD, 768);
    // MLP2: 128x128 tile (R3 config)
    gemm_mfma<2><<<dim3(6, 99), 256, 0, stream>>>(mid, MLPD, W2t, MLPD, X, b2 + i * 768,
                                                  nullptr, TOKS, 768, MLPD);
  }
  head_kernel<<<64, 64, 0, stream>>>(X, Wh, bhd, out);
}

// Round 8
// 1914.094 us; speedup vs baseline: 1.3509x; 1.0031x over previous
//
#include <hip/hip_runtime.h>
#include <cstddef>

#define BATCH 64
#define SEQL  197
#define EMB   768
#define NH    12
#define HDIM  64
#define NBLK  6
#define MLPD  3072
#define TOKS  12608   // BATCH*SEQL
#define PTOK  12544   // BATCH*196
#define ATT_SCALE 0.28867513459481287f  // 1/sqrt(H=12)
#define LOG2E 1.4426950408889634f

typedef short bf16x8 __attribute__((ext_vector_type(8)));
typedef float f32x4  __attribute__((ext_vector_type(4)));

__device__ inline float bf2f(unsigned short u) {
  union { unsigned int i; float f; } c; c.i = ((unsigned int)u) << 16; return c.f;
}
__device__ inline unsigned short f2bf(float f) {
  union { float f; unsigned int i; } c; c.f = f;
  unsigned int r = c.i + 0x7FFFu + ((c.i >> 16) & 1u);
  return (unsigned short)(r >> 16);
}

// gelu via A&S 7.1.26 erf (|err|<=1.5e-7): ~14 VALU ops vs ~25-30 for libm erff
__device__ __forceinline__ float gelu_f(float x) {
  float u = __builtin_fabsf(x) * 0.70710678118654752f;
  float t = __builtin_amdgcn_rcpf(__builtin_fmaf(0.3275911f, u, 1.0f));
  float p = __builtin_fmaf(1.061405429f, t, -1.453152027f);
  p = __builtin_fmaf(p, t, 1.421413741f);
  p = __builtin_fmaf(p, t, -0.284496736f);
  p = __builtin_fmaf(p, t, 0.254829592f);
  p = p * t;
  float e = __expf(-u * u);
  float er = __builtin_fmaf(-p, e, 1.0f);       // erf(|x|/sqrt2)
  er = __builtin_copysignf(er, x);
  return 0.5f * x * (1.0f + er);
}

__device__ __forceinline__ void gload16(const unsigned short* g, void* l) {
  __builtin_amdgcn_global_load_lds(
      (const __attribute__((address_space(1))) unsigned int*)g,
      (__attribute__((address_space(3))) unsigned int*)l, 16, 0, 0);
}

// ---------------- patchify: images (B,3,224,224) -> patches (12544, 768) bf16 ----------------
__global__ __launch_bounds__(256) void patchify_kernel(const float* __restrict__ img,
                                                       unsigned short* __restrict__ out) {
  int i4 = blockIdx.x * 256 + threadIdx.x;    // < 12544*768/4
  int f4 = i4 % 192;
  int r  = i4 / 192;
  int b  = r / 196, t = r - b * 196;
  int f  = f4 * 4;
  int c  = f >> 8;
  int rem = f & 255;
  int iy = rem >> 4, ix = rem & 15;
  int py = t / 14, px = t - py * 14;
  const float* src = img + ((((size_t)b * 3 + c) * 224 + py * 16 + iy) * 224 + px * 16 + ix);
  float4 v = *(const float4*)src;
  ushort4 u;
  u.x = f2bf(v.x); u.y = f2bf(v.y); u.z = f2bf(v.z); u.w = f2bf(v.w);
  *(ushort4*)(out + (size_t)r * 768 + f) = u;
}

// ---------------- cls token + pos row 0 ----------------
__global__ __launch_bounds__(256) void clspos_kernel(const float* __restrict__ cls,
                                                     const float* __restrict__ pos,
                                                     float* __restrict__ X) {
  int idx = blockIdx.x * 256 + threadIdx.x;   // < 64*768
  int b = idx / 768, e = idx - b * 768;
  X[(size_t)b * SEQL * 768 + e] = cls[e] + pos[e];
}

// ---------------- weight transpose+convert: W (K,N) fp32 -> Wt (N,K) bf16 ----------------
// perm=1: store k at pi-permuted position within each 64-block:
//   k' = (k&~63) | ((k&15)*4 + ((k>>4)&3))   -- must match gemm MODE-1 mid store order
__global__ __launch_bounds__(256) void wconv_kernel(const float* __restrict__ W,
                                                    unsigned short* __restrict__ Wt,
                                                    int K, int N, int perm) {
  __shared__ float t[32][33];
  int k0 = blockIdx.x * 32, n0 = blockIdx.y * 32;
  int kk = threadIdx.x >> 3, nn = (threadIdx.x & 7) * 4;
  float4 v = *(const float4*)&W[(size_t)(k0 + kk) * N + n0 + nn];
  t[nn + 0][kk] = v.x; t[nn + 1][kk] = v.y; t[nn + 2][kk] = v.z; t[nn + 3][kk] = v.w;
  __syncthreads();
  int nr = threadIdx.x >> 3, kc = (threadIdx.x & 7) * 4;
  ushort4 u;
  u.x = f2bf(t[nr][kc + 0]); u.y = f2bf(t[nr][kc + 1]);
  u.z = f2bf(t[nr][kc + 2]); u.w = f2bf(t[nr][kc + 3]);
  if (!perm) {
    *(ushort4*)&Wt[(size_t)(n0 + nr) * K + k0 + kc] = u;
  } else {
    size_t base = (size_t)(n0 + nr) * K + (size_t)(k0 & ~63);
    int klo = (k0 & 32) + kc;                    // 0..63, multiple of 4
    size_t st = base + (size_t)((klo & 15) * 4 + (klo >> 4));
    Wt[st + 0]  = u.x;
    Wt[st + 4]  = u.y;
    Wt[st + 8]  = u.z;
    Wt[st + 12] = u.w;
  }
}

// ---------------- qkv weight transpose: W[m][h][d][e] fp32 -> Wt[(m*12+h)][e][d] bf16 ------
__global__ __launch_bounds__(256) void qwconv_kernel(const float* __restrict__ Wq,
                                                     const float* __restrict__ Wk,
                                                     const float* __restrict__ Wv,
                                                     unsigned short* __restrict__ Wt) {
  int mh = blockIdx.x;            // 0..35
  int m = mh / 12, h = mh - m * 12;
  const float* src = (m == 0 ? Wq : (m == 1 ? Wk : Wv)) + (size_t)h * 4096;
  unsigned short* dst = Wt + (size_t)mh * 4096;
  for (int idx = threadIdx.x; idx < 4096; idx += 256) {
    int d = idx >> 6, e = idx & 63;
    dst[e * 64 + d] = f2bf(src[idx]);
  }
}

// ---------------- 128x128 bf16 MFMA GEMM (R3-verified single-buffer) ----------------
// MODE 0: X rows remapped b*197+1+t, C = acc + bias + pos[1+t]   (fp32 out)
// MODE 1: C = gelu(acc + bias)  -> bf16 out (mid, N=3072), pi-permuted cols, 8B stores
// MODE 2: C += acc + bias       -> fp32 residual (X, N=768)
template<int MODE>
__global__ __launch_bounds__(256) void gemm_mfma(const unsigned short* __restrict__ A, int lda,
                                                 const unsigned short* __restrict__ Bt, int ldb,
                                                 void* __restrict__ Cv,
                                                 const float* __restrict__ bias,
                                                 const float* __restrict__ pos,
                                                 int M, int N, int K) {
  __shared__ short As[8192];   // [128 rows][64 k] bf16, chunk-swizzled
  __shared__ short Bs[8192];
  const int tid  = threadIdx.x;
  const int wid  = tid >> 6, lane = tid & 63;
  const int wr   = wid >> 1, wc = wid & 1;
  const int fr   = lane & 15;
  const int fq   = lane >> 4;
  const int m0   = blockIdx.y * 128;
  const int n0   = blockIdx.x * 128;
  const int srow = lane >> 3;
  const int schk = lane & 7;
  const int Mc   = M - 1;

  f32x4 acc[4][4];
#pragma unroll
  for (int m = 0; m < 4; ++m)
#pragma unroll
    for (int n = 0; n < 4; ++n) acc[m][n] = (f32x4)0.f;

  for (int k0 = 0; k0 < K; k0 += 64) {
#pragma unroll
    for (int i = 0; i < 4; ++i) {
      int row = i * 32 + wid * 8 + srow;
      int gr = m0 + row; if (gr > Mc) gr = Mc;
      gload16(A + (size_t)gr * lda + k0 + ((schk ^ (row & 7)) << 3),
              (char*)As + i * 4096 + wid * 1024);
      gload16(Bt + (size_t)(n0 + row) * ldb + k0 + ((schk ^ (row & 7)) << 3),
              (char*)Bs + i * 4096 + wid * 1024);
    }
    __syncthreads();
#pragma unroll
    for (int ks = 0; ks < 2; ++ks) {
      bf16x8 af[4], bfr[4];
#pragma unroll
      for (int m = 0; m < 4; ++m) {
        int row = (wr << 6) + (m << 4) + fr;
        int ch = ((ks << 2) + fq) ^ (row & 7);
        af[m] = *(const bf16x8*)&As[(row << 6) + (ch << 3)];
      }
#pragma unroll
      for (int n = 0; n < 4; ++n) {
        int row = (wc << 6) + (n << 4) + fr;
        int ch = ((ks << 2) + fq) ^ (row & 7);
        bfr[n] = *(const bf16x8*)&Bs[(row << 6) + (ch << 3)];
      }
#pragma unroll
      for (int m = 0; m < 4; ++m)
#pragma unroll
        for (int n = 0; n < 4; ++n)
          acc[m][n] = __builtin_amdgcn_mfma_f32_16x16x32_bf16(af[m], bfr[n], acc[m][n], 0, 0, 0);
    }
    __syncthreads();
  }

#pragma unroll
  for (int m = 0; m < 4; ++m) {
#pragma unroll
    for (int j = 0; j < 4; ++j) {
      int r = m0 + (wr << 6) + (m << 4) + (fq << 2) + j;
      if (r >= M) continue;
      if (MODE == 1) {
        // coalesced pi-permuted store: stored col (within 64-block) = fr*4 + n
        ushort4 q;
        float v0 = acc[0 * 0 + m][0][j] + bias[n0 + (wc << 6) + 0 * 16 + fr];
        float v1 = acc[m][1][j] + bias[n0 + (wc << 6) + 1 * 16 + fr];
        float v2 = acc[m][2][j] + bias[n0 + (wc << 6) + 2 * 16 + fr];
        float v3 = acc[m][3][j] + bias[n0 + (wc << 6) + 3 * 16 + fr];
        q.x = f2bf(gelu_f(v0));
        q.y = f2bf(gelu_f(v1));
        q.z = f2bf(gelu_f(v2));
        q.w = f2bf(gelu_f(v3));
        *(ushort4*)&((unsigned short*)Cv)[(size_t)r * MLPD + n0 + (wc << 6) + fr * 4] = q;
      } else {
#pragma unroll
        for (int n = 0; n < 4; ++n) {
          int c = n0 + (wc << 6) + (n << 4) + fr;
          float v = acc[m][n][j] + bias[c];
          if (MODE == 0) {
            int b = r / 196, t = r - b * 196;
            ((float*)Cv)[((size_t)b * SEQL + 1 + t) * 768 + c] = v + pos[(size_t)(1 + t) * 768 + c];
          } else {
            ((float*)Cv)[(size_t)r * 768 + c] += v;
          }
        }
      }
    }
  }
}

// ---------------- LayerNorm: one wave per token, fp32 in -> bf16 out ----------------
__global__ __launch_bounds__(256) void ln_kernel(const float* __restrict__ Xi,
                                                 unsigned short* __restrict__ Ho,
                                                 const float* __restrict__ g,
                                                 const float* __restrict__ bb) {
  int tok = blockIdx.x * 4 + (threadIdx.x >> 6);
  int lane = threadIdx.x & 63;
  const float* x = Xi + (size_t)tok * 768;
  float4 v0 = *(const float4*)(x + lane * 4);
  float4 v1 = *(const float4*)(x + 256 + lane * 4);
  float4 v2 = *(const float4*)(x + 512 + lane * 4);
  float s = v0.x + v0.y + v0.z + v0.w + v1.x + v1.y + v1.z + v1.w + v2.x + v2.y + v2.z + v2.w;
  float q = v0.x*v0.x + v0.y*v0.y + v0.z*v0.z + v0.w*v0.w
          + v1.x*v1.x + v1.y*v1.y + v1.z*v1.z + v1.w*v1.w
          + v2.x*v2.x + v2.y*v2.y + v2.z*v2.z + v2.w*v2.w;
#pragma unroll
  for (int o = 32; o > 0; o >>= 1) { s += __shfl_xor(s, o); q += __shfl_xor(q, o); }
  float mean = s * (1.f / 768.f);
  float var  = q * (1.f / 768.f) - mean * mean;
  float rs = rsqrtf(var + 1e-5f);
  unsigned short* outp = Ho + (size_t)tok * 768;
  float4 g0 = *(const float4*)(g + lane * 4);
  float4 g1 = *(const float4*)(g + 256 + lane * 4);
  float4 g2 = *(const float4*)(g + 512 + lane * 4);
  float4 b0 = *(const float4*)(bb + lane * 4);
  float4 b1 = *(const float4*)(bb + 256 + lane * 4);
  float4 b2 = *(const float4*)(bb + 512 + lane * 4);
  ushort4 s0, s1, s2;
  s0.x = f2bf((v0.x - mean) * rs * g0.x + b0.x); s0.y = f2bf((v0.y - mean) * rs * g0.y + b0.y);
  s0.z = f2bf((v0.z - mean) * rs * g0.z + b0.z); s0.w = f2bf((v0.w - mean) * rs * g0.w + b0.w);
  s1.x = f2bf((v1.x - mean) * rs * g1.x + b1.x); s1.y = f2bf((v1.y - mean) * rs * g1.y + b1.y);
  s1.z = f2bf((v1.z - mean) * rs * g1.z + b1.z); s1.w = f2bf((v1.w - mean) * rs * g1.w + b1.w);
  s2.x = f2bf((v2.x - mean) * rs * g2.x + b2.x); s2.y = f2bf((v2.y - mean) * rs * g2.y + b2.y);
  s2.z = f2bf((v2.z - mean) * rs * g2.z + b2.z); s2.w = f2bf((v2.w - mean) * rs * g2.w + b2.w);
  *(ushort4*)(outp + lane * 4) = s0;
  *(ushort4*)(outp + 256 + lane * 4) = s1;
  *(ushort4*)(outp + 512 + lane * 4) = s2;
}

// ---------------- MFMA QKV: WG = 64 tokens x head; wave = 16 tokens, q/k/v -----------
// Q,K written pi-permuted along d (contraction-invariant in QK^T); V true layout.
__global__ __launch_bounds__(256) void qkv_mfma(const unsigned short* __restrict__ Hb,
    const unsigned short* __restrict__ Wt,
    const float* __restrict__ bq, const float* __restrict__ bk, const float* __restrict__ bv,
    unsigned short* __restrict__ Qo, unsigned short* __restrict__ Ko,
    unsigned short* __restrict__ Vo) {
  const int h = blockIdx.y;
  const int tid = threadIdx.x, wv = tid >> 6, lane = tid & 63;
  const int fr = lane & 15, hi = lane >> 4;
  const int t0 = blockIdx.x * 64 + wv * 16;            // 197*64 = 12608 exact
  const unsigned short* arow = Hb + (size_t)(t0 + fr) * 768 + h * 64;
  bf16x8 a0 = *(const bf16x8*)(arow + hi * 8);
  bf16x8 a1 = *(const bf16x8*)(arow + 32 + hi * 8);
  f32x4 acc[3][4];
#pragma unroll
  for (int m = 0; m < 3; ++m)
#pragma unroll
    for (int n = 0; n < 4; ++n) acc[m][n] = (f32x4)0.f;
#pragma unroll
  for (int m = 0; m < 3; ++m) {
    const unsigned short* wb = Wt + (size_t)(m * 12 + h) * 4096;
#pragma unroll
    for (int n = 0; n < 4; ++n) {
      bf16x8 b0 = *(const bf16x8*)&wb[(n * 16 + fr) * 64 + hi * 8];
      bf16x8 b1 = *(const bf16x8*)&wb[(n * 16 + fr) * 64 + 32 + hi * 8];
      acc[m][n] = __builtin_amdgcn_mfma_f32_16x16x32_bf16(a0, b0, acc[m][n], 0, 0, 0);
      acc[m][n] = __builtin_amdgcn_mfma_f32_16x16x32_bf16(a1, b1, acc[m][n], 0, 0, 0);
    }
  }
#pragma unroll
  for (int m = 0; m < 3; ++m) {
    const float* bptr = (m == 0 ? bq : (m == 1 ? bk : bv)) + h * 64;
    unsigned short* optr = (m == 0 ? Qo : (m == 1 ? Ko : Vo));
    const float sc = (m == 0) ? ATT_SCALE : 1.f;
#pragma unroll
    for (int j = 0; j < 4; ++j) {
      int tk = t0 + hi * 4 + j;
      int b = tk / 197, s = tk - b * 197;
      size_t base_o = (((size_t)b * NH + h) * SEQL + s) * 64;
      if (m < 2) {
        // coalesced pi-permuted store: stored d = fr*4 + n
        ushort4 o;
        o.x = f2bf((acc[m][0][j] + bptr[0 * 16 + fr]) * sc);
        o.y = f2bf((acc[m][1][j] + bptr[1 * 16 + fr]) * sc);
        o.z = f2bf((acc[m][2][j] + bptr[2 * 16 + fr]) * sc);
        o.w = f2bf((acc[m][3][j] + bptr[3 * 16 + fr]) * sc);
        *(ushort4*)&optr[base_o + fr * 4] = o;
      } else {
#pragma unroll
        for (int n = 0; n < 4; ++n)
          optr[base_o + n * 16 + fr] = f2bf(acc[m][n][j] + bptr[n * 16 + fr]);
      }
    }
  }
}

// ---------------- MFMA attention: one WG (4 waves) per (b,h) ----------------
// Q,K arrive pi-permuted along d (dot products unchanged); V true layout.
__global__ __launch_bounds__(256) void attn_kernel(const unsigned short* __restrict__ Q,
                                                   const unsigned short* __restrict__ Kg,
                                                   const unsigned short* __restrict__ Vg,
                                                   float* __restrict__ X) {
  __shared__ unsigned short Vt[64][232];      // V^T; cols 197..232 zero
  __shared__ unsigned short Pl[4][16][232];   // per-wave P; cols >=208 zero
  const int bh = blockIdx.x;
  const int b = bh / NH, h = bh - b * NH;
  const int tid = threadIdx.x, wv = tid >> 6, lane = tid & 63;
  const int fr = lane & 15, hi = lane >> 4;
  const unsigned short* Qp = Q  + (size_t)bh * SEQL * 64;
  const unsigned short* Kp = Kg + (size_t)bh * SEQL * 64;
  const unsigned short* Vp = Vg + (size_t)bh * SEQL * 64;

  for (int idx = tid; idx < SEQL * 16; idx += 256) {
    int s = idx >> 4, d4 = (idx & 15) * 4;
    ushort4 v = *(const ushort4*)&Vp[s * 64 + d4];
    Vt[d4 + 0][s] = v.x; Vt[d4 + 1][s] = v.y; Vt[d4 + 2][s] = v.z; Vt[d4 + 3][s] = v.w;
  }
  for (int idx = tid; idx < 64 * 35; idx += 256) {
    int d = idx / 35, c = 197 + idx % 35;
    Vt[d][c] = 0;
  }
  for (int idx = lane; idx < 16 * 24; idx += 64) {
    int r = idx / 24, c = 208 + idx % 24;
    Pl[wv][r][c] = 0;
  }
  __syncthreads();

  for (int qt = wv; qt < 13; qt += 4) {
    int qrow = qt * 16 + fr; if (qrow > 196) qrow = 196;
    bf16x8 qa0 = *(const bf16x8*)&Qp[qrow * 64 + hi * 8];
    bf16x8 qa1 = *(const bf16x8*)&Qp[qrow * 64 + 32 + hi * 8];
    f32x4 sc[13];
#pragma unroll
    for (int kt = 0; kt < 13; ++kt) {
      int krow = kt * 16 + fr; if (krow > 196) krow = 196;
      bf16x8 kb0 = *(const bf16x8*)&Kp[krow * 64 + hi * 8];
      bf16x8 kb1 = *(const bf16x8*)&Kp[krow * 64 + 32 + hi * 8];
      f32x4 a = (f32x4)0.f;
      a = __builtin_amdgcn_mfma_f32_16x16x32_bf16(qa0, kb0, a, 0, 0, 0);
      a = __builtin_amdgcn_mfma_f32_16x16x32_bf16(qa1, kb1, a, 0, 0, 0);
      sc[kt] = a;
    }
    float mx[4] = {-3e38f, -3e38f, -3e38f, -3e38f};
#pragma unroll
    for (int kt = 0; kt < 13; ++kt) {
      bool inval = (kt == 12) && (fr >= 5);
#pragma unroll
      for (int j = 0; j < 4; ++j) {
        float s = inval ? -3e38f : sc[kt][j];
        sc[kt][j] = s;
        mx[j] = fmaxf(mx[j], s);
      }
    }
#pragma unroll
    for (int o = 8; o > 0; o >>= 1)
#pragma unroll
      for (int j = 0; j < 4; ++j) mx[j] = fmaxf(mx[j], __shfl_xor(mx[j], o));
    float l[4] = {0.f, 0.f, 0.f, 0.f};
#pragma unroll
    for (int kt = 0; kt < 13; ++kt) {
#pragma unroll
      for (int j = 0; j < 4; ++j) {
        float p = exp2f((sc[kt][j] - mx[j]) * LOG2E);
        if ((kt == 12) && (fr >= 5)) p = 0.f;
        l[j] += p;
        Pl[wv][hi * 4 + j][kt * 16 + fr] = f2bf(p);
      }
    }
#pragma unroll
    for (int o = 8; o > 0; o >>= 1)
#pragma unroll
      for (int j = 0; j < 4; ++j) l[j] += __shfl_xor(l[j], o);
    f32x4 ov[4];
#pragma unroll
    for (int n = 0; n < 4; ++n) ov[n] = (f32x4)0.f;
#pragma unroll
    for (int kc = 0; kc < 7; ++kc) {
      bf16x8 pa = *(const bf16x8*)&Pl[wv][fr][kc * 32 + hi * 8];
#pragma unroll
      for (int n = 0; n < 4; ++n) {
        bf16x8 vb = *(const bf16x8*)&Vt[n * 16 + fr][kc * 32 + hi * 8];
        ov[n] = __builtin_amdgcn_mfma_f32_16x16x32_bf16(pa, vb, ov[n], 0, 0, 0);
      }
    }
#pragma unroll
    for (int j = 0; j < 4; ++j) {
      int r = qt * 16 + hi * 4 + j;
      if (r >= SEQL) continue;
      float inv = 1.f / l[j];
      float* xp = X + ((size_t)b * SEQL + r) * 768 + h * 64 + fr;
#pragma unroll
      for (int n = 0; n < 4; ++n) xp[n * 16] += ov[n][j] * inv;
    }
  }
}

// ---------------- head: cls @ Whead + bhead -> softmax ----------------
__global__ __launch_bounds__(64) void head_kernel(const float* __restrict__ X,
                                                  const float* __restrict__ Wh,
                                                  const float* __restrict__ bh,
                                                  float* __restrict__ out) {
  __shared__ float lg[10];
  int b = blockIdx.x, t = threadIdx.x;
  if (t < 10) {
    float acc = bh[t];
    const float* x = X + (size_t)b * SEQL * 768;
    for (int d = 0; d < 768; ++d) acc += x[d] * Wh[d * 10 + t];
    lg[t] = acc;
  }
  __syncthreads();
  if (t == 0) {
    float m = lg[0];
    for (int c = 1; c < 10; ++c) m = fmaxf(m, lg[c]);
    float ssum = 0.f;
    for (int c = 0; c < 10; ++c) ssum += expf(lg[c] - m);
    for (int c = 0; c < 10; ++c) out[b * 10 + c] = expf(lg[c] - m) / ssum;
  }
}

extern "C" void kernel_launch(void* const* d_in, const int* in_sizes, int n_in,
                              void* d_out, int out_size, void* d_ws, size_t ws_size,
                              hipStream_t stream) {
  const float* images = (const float*)d_in[0];
  const float* Wmap = (const float*)d_in[1];
  const float* bmap = (const float*)d_in[2];
  const float* cls  = (const float*)d_in[3];
  const float* pos  = (const float*)d_in[4];
  const float* ln1g = (const float*)d_in[5];
  const float* ln1b = (const float*)d_in[6];
  const float* Wq   = (const float*)d_in[7];
  const float* bq   = (const float*)d_in[8];
  const float* Wk   = (const float*)d_in[9];
  const float* bk   = (const float*)d_in[10];
  const float* Wv   = (const float*)d_in[11];
  const float* bv   = (const float*)d_in[12];
  const float* ln2g = (const float*)d_in[13];
  const float* ln2b = (const float*)d_in[14];
  const float* W1   = (const float*)d_in[15];
  const float* b1   = (const float*)d_in[16];
  const float* W2   = (const float*)d_in[17];
  const float* b2   = (const float*)d_in[18];
  const float* Wh   = (const float*)d_in[19];
  const float* bhd  = (const float*)d_in[20];
  float* out = (float*)d_out;

  const size_t ACT = (size_t)TOKS * 768;
  const size_t oX = 0;
  const size_t oHb = oX + ACT * 4;
  const size_t oR  = oHb + ACT * 2;
  const size_t oW1 = oR + 3 * ACT * 4;
  const size_t oW2 = oW1 + (size_t)768 * 3072 * 2;
  const size_t oWm = oW2 + (size_t)768 * 3072 * 2;
  const size_t oQW = oWm + (size_t)768 * 768 * 2;
  const size_t need = oQW + (size_t)36 * 4096 * 2;
  if (ws_size < need) return;

  char* ws = (char*)d_ws;
  float* X = (float*)(ws + oX);
  unsigned short* Hb = (unsigned short*)(ws + oHb);
  unsigned short* Qb = (unsigned short*)(ws + oR);
  unsigned short* Kb = Qb + ACT;
  unsigned short* Vb = Kb + ACT;
  unsigned short* mid = (unsigned short*)(ws + oR);
  unsigned short* patches = (unsigned short*)(ws + oR);
  unsigned short* W1t = (unsigned short*)(ws + oW1);
  unsigned short* W2t = (unsigned short*)(ws + oW2);
  unsigned short* Wmapt = (unsigned short*)(ws + oWm);
  unsigned short* QWt = (unsigned short*)(ws + oQW);

  wconv_kernel<<<dim3(24, 24), 256, 0, stream>>>(Wmap, Wmapt, 768, 768, 0);
  patchify_kernel<<<9408, 256, 0, stream>>>(images, patches);
  clspos_kernel<<<192, 256, 0, stream>>>(cls, pos, X);
  gemm_mfma<0><<<dim3(6, 98), 256, 0, stream>>>(patches, 768, Wmapt, 768, X, bmap, pos,
                                                PTOK, 768, 768);

  for (int i = 0; i < NBLK; ++i) {
    ln_kernel<<<3152, 256, 0, stream>>>(X, Hb, ln1g + i * 768, ln1b + i * 768);
    qwconv_kernel<<<36, 256, 0, stream>>>(Wq + (size_t)i * 49152, Wk + (size_t)i * 49152,
                                          Wv + (size_t)i * 49152, QWt);
    qkv_mfma<<<dim3(197, 12), 256, 0, stream>>>(Hb, QWt,
        bq + i * 768, bk + i * 768, bv + i * 768, Qb, Kb, Vb);
    attn_kernel<<<768, 256, 0, stream>>>(Qb, Kb, Vb, X);
    ln_kernel<<<3152, 256, 0, stream>>>(X, Hb, ln2g + i * 768, ln2b + i * 768);
    wconv_kernel<<<dim3(24, 96), 256, 0, stream>>>(W1 + (size_t)i * 2359296, W1t, 768, MLPD, 0);
    // W2t gets the SAME pi-permutation on k that MODE-1 applies to mid's columns
    wconv_kernel<<<dim3(96, 24), 256, 0, stream>>>(W2 + (size_t)i * 2359296, W2t, MLPD, 768, 1);
    // MLP1: 128x128 tile + cheap gelu + coalesced pi-permuted 8B stores
    gemm_mfma<1><<<dim3(24, 99), 256, 0, stream>>>(Hb, 768, W1t, 768, mid, b1 + i * MLPD,
                                                   nullptr, TOKS, MLPD, 768);
    // MLP2: 128x128 tile (consumes permuted mid + permuted W2t -> true-layout X)
    gemm_mfma<2><<<dim3(6, 99), 256, 0, stream>>>(mid, MLPD, W2t, MLPD, X, b2 + i * 768,
                                                  nullptr, TOKS, 768, MLPD);
  }
  head_kernel<<<64, 64, 0, stream>>>(X, Wh, bhd, out);
}